// Round 12
// baseline (302.083 us; speedup 1.0000x reference)
//
#include <hip/hip_runtime.h>
#include <cmath>

#pragma clang fp contract(off)

typedef unsigned int u32;
typedef unsigned short u16;
typedef unsigned long long u64;

#define K_PER_LVL 1000
#define KTOT 5000            // 5 levels * 1000
#define NIMG 2
#define BINS 2048            // histogram bins = top 11 bits of fkey
#define BIN_SHIFT 21
#define EQ_CAP 2048
#define ECAP 32768           // max suppression edges per image (est ~4k; 8x margin)
#define LECAP 24576          // edges held in LDS; overflow spills to global
#define CBUF 1024            // per-block staging capacity in k_compact

__constant__ int c_LG[5] = {512, 256, 128, 64, 32};      // grid dim (square)
__constant__ int c_LS[5] = {4, 8, 16, 32, 64};           // stride
__constant__ int c_LZ[5] = {32, 64, 128, 256, 512};      // anchor size
__constant__ int c_LM[5] = {786432, 196608, 49152, 12288, 3072}; // 3*G*G

struct Ptrs { const float* o[5]; const float* b[5]; };

// monotone float -> uint key (larger float => larger key)
__device__ inline u32 fkey(float f) {
    u32 u = __float_as_uint(f);
    return (u & 0x80000000u) ? ~u : (u | 0x80000000u);
}

// ---------------- zero hist + counters ----------------
__global__ __launch_bounds__(256) void k_zero(u32* __restrict__ z, int nwords) {
    int i = blockIdx.x * 256 + threadIdx.x;
    int stride = gridDim.x * 256;
    for (; i < nwords; i += stride) z[i] = 0;
}

// ---------------- one-pass 2048-bin histogram (float4 loads, LDS pre-agg) ----------------
__global__ __launch_bounds__(256) void k_hist(Ptrs P, u32* __restrict__ hist) {
    int p = blockIdx.y; int l = p % 5; int n = p / 5;
    int M4 = c_LM[l] >> 2;
    const float4* base = (const float4*)(P.o[l] + (size_t)n * c_LM[l]);
    __shared__ u32 lh[BINS];
    for (int i = threadIdx.x; i < BINS; i += 256) lh[i] = 0;
    __syncthreads();
    int stride = gridDim.x * 256;
    for (int i = blockIdx.x * 256 + threadIdx.x; i < M4; i += stride) {
        float4 v = base[i];
        atomicAdd(&lh[fkey(v.x) >> BIN_SHIFT], 1u);
        atomicAdd(&lh[fkey(v.y) >> BIN_SHIFT], 1u);
        atomicAdd(&lh[fkey(v.z) >> BIN_SHIFT], 1u);
        atomicAdd(&lh[fkey(v.w) >> BIN_SHIFT], 1u);
    }
    __syncthreads();
    for (int i = threadIdx.x; i < BINS; i += 256) {
        u32 c = lh[i];
        if (c) atomicAdd(&hist[p * BINS + i], c);
    }
}

// ---------------- resolve: threshold bin B, G = #(keys above B), KF = 1000 - G ----------------
__global__ __launch_bounds__(256) void k_resolve(const u32* __restrict__ hist,
                                                 int* __restrict__ binB, int* __restrict__ kneed,
                                                 int* __restrict__ g0) {
    int p = blockIdx.x, t = threadIdx.x;
    __shared__ u32 lh[BINS];
    __shared__ u32 seg[256];
    for (int i = t; i < BINS; i += 256) lh[i] = hist[p * BINS + i];
    __syncthreads();
    u32 s = 0;
    for (int q = 0; q < 8; ++q) s += lh[t * 8 + q];
    seg[t] = s;
    __syncthreads();
    if (t == 0) {
        u32 G = 0; int B = 0;
        for (int sg = 255; sg >= 0; --sg) {
            if (G + seg[sg] >= (u32)K_PER_LVL) {
                for (int b = sg * 8 + 7; b >= sg * 8; --b) {
                    u32 c = lh[b];
                    if (G + c >= (u32)K_PER_LVL) { B = b; break; }
                    G += c;
                }
                break;
            }
            G += seg[sg];
        }
        binB[p] = B;
        kneed[p] = K_PER_LVL - (int)G;   // KF taken from boundary bin
        g0[p] = (int)G;                  // count strictly above bin B
    }
}

// ---------------- compact: block-local LDS staging, ONE reservation atomic per block ----------------
__global__ __launch_bounds__(256) void k_compact(Ptrs P, const int* __restrict__ binB,
                                                 u32* gcnt, u32* ecnt,
                                                 int* __restrict__ sel, u64* __restrict__ eq) {
    int p = blockIdx.y; int l = p % 5; int n = p / 5;
    int M4 = c_LM[l] >> 2; int gg = c_LM[l] / 3;
    const float4* base = (const float4*)(P.o[l] + (size_t)n * c_LM[l]);
    int B = binB[p];
    __shared__ u32 lsel[CBUF];
    __shared__ u64 leq[CBUF];
    __shared__ u32 cSel, cEq, baseSel, baseEq;
    if (threadIdx.x == 0) { cSel = 0; cEq = 0; }
    __syncthreads();
    int stride = gridDim.x * 256;
    for (int i4 = blockIdx.x * 256 + threadIdx.x; i4 < M4; i4 += stride) {
        float4 v = base[i4];
        float vv[4] = {v.x, v.y, v.z, v.w};
        #pragma unroll
        for (int q = 0; q < 4; ++q) {
            u32 k = fkey(vv[q]);
            int bin = (int)(k >> BIN_SHIFT);
            if (bin < B) continue;
            int i = i4 * 4 + q;
            // input linear i = a*gg + pix ; flattened m = pix*3 + a  (h,w,a order)
            int a = i / gg; int pix = i - a * gg; int m = pix * 3 + a;
            if (bin > B) {
                u32 t = atomicAdd(&cSel, 1u);
                if (t < CBUF) lsel[t] = (u32)m;
                else { u32 pos = atomicAdd(&gcnt[p], 1u); sel[p * K_PER_LVL + pos] = m; }
            } else {
                u64 pk = ((u64)k << 20) | (u64)(0xFFFFFu ^ (u32)m);
                u32 t = atomicAdd(&cEq, 1u);
                if (t < CBUF) leq[t] = pk;
                else { u32 e = atomicAdd(&ecnt[p], 1u); if (e < EQ_CAP) eq[(size_t)p * EQ_CAP + e] = pk; }
            }
        }
    }
    __syncthreads();
    if (threadIdx.x == 0) {
        u32 ns = cSel < CBUF ? cSel : CBUF;
        u32 ne = cEq < CBUF ? cEq : CBUF;
        baseSel = ns ? atomicAdd(&gcnt[p], ns) : 0u;
        baseEq  = ne ? atomicAdd(&ecnt[p], ne) : 0u;
    }
    __syncthreads();
    u32 ns = cSel < CBUF ? cSel : CBUF;
    u32 ne = cEq < CBUF ? cEq : CBUF;
    for (u32 i = threadIdx.x; i < ns; i += 256) sel[p * K_PER_LVL + baseSel + i] = (int)lsel[i];
    for (u32 i = threadIdx.x; i < ne; i += 256) {
        u32 slot = baseEq + i;
        if (slot < EQ_CAP) eq[(size_t)p * EQ_CAP + slot] = leq[i];
    }
}

// ---------------- boundary bin: rank-by-count selection (keys unique), take KF lowest ranks ----------------
__global__ __launch_bounds__(256) void k_eqsel(const u32* __restrict__ ecnt, const int* __restrict__ kneed,
                                               const int* __restrict__ g0,
                                               const u64* __restrict__ eq, int* __restrict__ sel) {
    int p = blockIdx.x, t = threadIdx.x;
    int E = (int)ecnt[p]; if (E > EQ_CAP) E = EQ_CAP;
    int KF = kneed[p]; int G0 = g0[p];
    __shared__ u64 a[EQ_CAP];
    for (int i = t; i < E; i += 256) a[i] = eq[(size_t)p * EQ_CAP + i];
    __syncthreads();
    u64 mine[8]; int rk[8];
    #pragma unroll
    for (int q = 0; q < 8; ++q) {
        int i = t + q * 256;
        mine[q] = (i < E) ? a[i] : 0ULL;
        rk[q] = 0;
    }
    for (int j = 0; j < E; ++j) {
        u64 v = a[j];                            // uniform index -> LDS broadcast
        #pragma unroll
        for (int q = 0; q < 8; ++q) rk[q] += (v > mine[q]) ? 1 : 0;
    }
    #pragma unroll
    for (int q = 0; q < 8; ++q) {
        int i = t + q * 256;
        if (i < E && rk[q] < KF) {
            int m = (int)(0xFFFFFu ^ (u32)(mine[q] & 0xFFFFFu));
            sel[p * K_PER_LVL + G0 + rk[q]] = m;
        }
    }
}

// ---------------- featurize: anchors + decode + clip + score + 64b order key ----------------
__global__ void k_feat(Ptrs P, const int* __restrict__ sel, u64* __restrict__ key64,
                       float* __restrict__ csc, float* __restrict__ cbox, float* __restrict__ cobox) {
    int tid = blockIdx.x * 256 + threadIdx.x;
    if (tid >= NIMG * KTOT) return;
    int p = tid / K_PER_LVL, s = tid - p * K_PER_LVL;
    int n = p / 5, l = p % 5;
    int G = c_LG[l], S = c_LS[l], Z = c_LZ[l];
    int gg = G * G;
    int m = sel[p * K_PER_LVL + s];
    int a = m % 3; int pix = m / 3; int h = pix / G; int w = pix - h * G;

    // anchor base: hr=sqrt(ar), wr=1/hr, round-half-even (matches jnp f32)
    const float ars[3] = {0.5f, 1.0f, 2.0f};
    float ar = ars[a];
    float hr = sqrtf(ar), wr = 1.0f / hr;
    float wsz = wr * (float)Z, hsz = hr * (float)Z;
    float bx1 = rintf(-0.5f * wsz), by1 = rintf(-0.5f * hsz);
    float bx2 = rintf(0.5f * wsz),  by2 = rintf(0.5f * hsz);
    float sx = (float)(w * S), sy = (float)(h * S);
    float ax1 = sx + bx1, ay1 = sy + by1, ax2 = sx + bx2, ay2 = sy + by2;
    float wa = ax2 - ax1, ha = ay2 - ay1;
    float cxa = ax1 + 0.5f * wa, cya = ay1 + 0.5f * ha;

    const float* bb = P.b[l] + (size_t)n * 12 * gg;
    float dx = bb[(a * 4 + 0) * gg + pix];
    float dy = bb[(a * 4 + 1) * gg + pix];
    const float CLIPV = 4.135166556742356f;  // log(1000/16)
    float dw = fminf(bb[(a * 4 + 2) * gg + pix], CLIPV);
    float dh = fminf(bb[(a * 4 + 3) * gg + pix], CLIPV);
    float cx = dx * wa + cxa, cy = dy * ha + cya;
    float ww = expf(dw) * wa, hh = expf(dh) * ha;
    float x1 = cx - 0.5f * ww, y1 = cy - 0.5f * hh;
    float x2 = cx + 0.5f * ww, y2 = cy + 0.5f * hh;
    x1 = fminf(fmaxf(x1, 0.f), 2048.f);
    y1 = fminf(fmaxf(y1, 0.f), 2048.f);
    x2 = fminf(fmaxf(x2, 0.f), 2048.f);
    y2 = fminf(fmaxf(y2, 0.f), 2048.f);

    float raw = P.o[l][(size_t)n * 3 * gg + a * gg + pix];
    float sc = 1.0f / (1.0f + expf(-raw));
    bool keep = (x2 - x1 >= 1e-3f) && (y2 - y1 >= 1e-3f) && (sc > 0.0f);

    int slot = n * KTOT + l * K_PER_LVL + s;
    // total order key: raw desc, then (level asc, m asc) == reference concat-position order
    u32 tb = ((u32)l << 20) | (u32)m;          // m < 2^20, l < 8  -> 23 bits, unique
    u32 kk = keep ? fkey(raw) : 0u;            // invalid sinks below every valid (finite raw)
    key64[slot] = ((u64)kk << 23) | (u64)(tb ^ 0x7FFFFFu);

    csc[slot] = keep ? sc : -INFINITY;
    cbox[slot * 4 + 0] = x1; cbox[slot * 4 + 1] = y1;
    cbox[slot * 4 + 2] = x2; cbox[slot * 4 + 3] = y2;
    float off = 4097.0f * (float)l;            // lvl * (W+H+1), batched_nms offset
    cobox[slot * 4 + 0] = x1 + off; cobox[slot * 4 + 1] = y1 + off;
    cobox[slot * 4 + 2] = x2 + off; cobox[slot * 4 + 3] = y2 + off;
}

// ---------------- exact rank: wave-uniform GLOBAL key stream (scalar-load pipe), 4-way j-split ----------------
// rounds 10/11: LDS j-stream is DS-pipe-issue-bound (~6.8 cyc/key at the DVFS
// clock); unrolling was neutral. Here the key stream is wave-uniform -> compiler
// emits s_load (scalar cache, off the DS/VMEM-vector pipes), and each thread
// scans only KTOT/4 keys (4 wave-groups, partial ranks summed via 4 KB LDS).
__global__ __launch_bounds__(1024) void k_rank(const u64* __restrict__ key64, const float* __restrict__ csc,
                       const float* __restrict__ cbox, const float* __restrict__ cobox,
                       float* __restrict__ ssc, float* __restrict__ sbox, float* __restrict__ sobox) {
    int n = blockIdx.y;
    int tid = threadIdx.x;
    int cand = tid & 255;            // candidate slot within block
    int ch = tid >> 8;               // j-chunk 0..3 (wave-uniform)
    int i = blockIdx.x * 256 + cand;
    __shared__ u32 part[4][256];
    const u64* kb = key64 + (size_t)n * KTOT;
    u64 ki = (i < KTOT) ? kb[i] : ~0ULL;         // sentinel: nothing > ~0
    int j0 = ch * (KTOT / 4), j1 = j0 + (KTOT / 4);   // 1250 each
    u32 r = 0;
    #pragma unroll 10
    for (int j = j0; j < j1; ++j) r += (kb[j] > ki) ? 1u : 0u;   // kb[j] wave-uniform -> s_load
    part[ch][cand] = r;
    __syncthreads();
    if (ch == 0 && i < KTOT) {
        int rank = (int)(part[0][cand] + part[1][cand] + part[2][cand] + part[3][cand]);
        int src = n * KTOT + i, dst = n * KTOT + rank;
        ssc[dst] = csc[src];
        sbox[dst * 4 + 0] = cbox[src * 4 + 0]; sbox[dst * 4 + 1] = cbox[src * 4 + 1];
        sbox[dst * 4 + 2] = cbox[src * 4 + 2]; sbox[dst * 4 + 3] = cbox[src * 4 + 3];
        sobox[dst * 4 + 0] = cobox[src * 4 + 0]; sobox[dst * 4 + 1] = cobox[src * 4 + 1];
        sobox[dst * 4 + 2] = cobox[src * 4 + 2]; sobox[dst * 4 + 3] = cobox[src * 4 + 3];
    }
}

// ---------------- sparse suppression edges: forward pairs (i<j) with IoU>0.7 ----------------
__global__ void k_edge(const float* __restrict__ sobox, u32* __restrict__ gE, u32* __restrict__ gPairs) {
    int n = blockIdx.z;
    int bi = blockIdx.x, bj = blockIdx.y;
    if (bj < bi) return;                         // forward-only (upper triangle)
    int i = bi * 64 + threadIdx.x;
    int j0 = bj * 64;
    __shared__ float cb[64][4];
    int jl = j0 + threadIdx.x;
    if (jl < KTOT) {
        cb[threadIdx.x][0] = sobox[(size_t)(n * KTOT + jl) * 4 + 0];
        cb[threadIdx.x][1] = sobox[(size_t)(n * KTOT + jl) * 4 + 1];
        cb[threadIdx.x][2] = sobox[(size_t)(n * KTOT + jl) * 4 + 2];
        cb[threadIdx.x][3] = sobox[(size_t)(n * KTOT + jl) * 4 + 3];
    } else {
        cb[threadIdx.x][0] = 0.f; cb[threadIdx.x][1] = 0.f;
        cb[threadIdx.x][2] = 0.f; cb[threadIdx.x][3] = 0.f;
    }
    __syncthreads();
    if (i >= KTOT) return;
    float x1 = sobox[(size_t)(n * KTOT + i) * 4 + 0];
    float y1 = sobox[(size_t)(n * KTOT + i) * 4 + 1];
    float x2 = sobox[(size_t)(n * KTOT + i) * 4 + 2];
    float y2 = sobox[(size_t)(n * KTOT + i) * 4 + 3];
    float areai = fmaxf(x2 - x1, 0.f) * fmaxf(y2 - y1, 0.f);
    int lim = KTOT - j0; if (lim > 64) lim = 64;
    for (int jj = 0; jj < lim; ++jj) {
        int j = j0 + jj;
        if (j <= i) continue;
        float bx1 = cb[jj][0], by1 = cb[jj][1], bx2 = cb[jj][2], by2 = cb[jj][3];
        float areaj = fmaxf(bx2 - bx1, 0.f) * fmaxf(by2 - by1, 0.f);
        float ltx = fmaxf(x1, bx1), lty = fmaxf(y1, by1);
        float rbx = fminf(x2, bx2), rby = fminf(y2, by2);
        float iw = fmaxf(rbx - ltx, 0.f), ih = fmaxf(rby - lty, 0.f);
        float inter = iw * ih;
        float iou = inter / (areai + areaj - inter + 1e-9f);
        if (iou > 0.7f) {
            u32 pos = atomicAdd(&gE[n], 1u);
            if (pos < ECAP) gPairs[(size_t)n * ECAP + pos] = ((u32)i << 13) | (u32)j;
        }
    }
}

// ---------------- greedy NMS sweep over sparse CSR (zero global mem on sweep path) ----------------
__global__ __launch_bounds__(256, 1) void k_nms(const float* __restrict__ ssc,
                      const float* __restrict__ sbox,
                      const u32* __restrict__ gE, const u32* __restrict__ gPairs,
                      u16* __restrict__ gEdges, float* __restrict__ out) {
    int n = blockIdx.x, tid = threadIdx.x;
    int lane = tid & 63, wv = tid >> 6;          // 4 waves
    __shared__ u32 cnt[KTOT];                    // 20 KB (count, then fill cursor)
    __shared__ u32 offs[KTOT + 1];               // 20 KB
    __shared__ u16 edges[LECAP];                 // 48 KB
    __shared__ u32 rem32[160];                   // dead bitmap (2 u32 per 64-word)
    __shared__ u32 colLo[64], colHi[64];
    __shared__ u32 scanb[256];
    __shared__ int picksS;

    // zero cnt + rem tail
    for (int i = tid; i < KTOT; i += 256) cnt[i] = 0;
    if (tid < 160) rem32[tid] = 0xFFFFFFFFu;     // default dead; real words overwritten
    __syncthreads();
    // dead-map init from scores (wave-parallel ballots)
    for (int w = wv; w < 79; w += 4) {
        int i = w * 64 + lane;
        bool dead = (i >= KTOT) || !(ssc[n * KTOT + i] > -INFINITY);
        u64 db = __ballot(dead);
        if (lane == 0) { rem32[2 * w] = (u32)db; rem32[2 * w + 1] = (u32)(db >> 32); }
    }
    __syncthreads();

    // ---- CSR build from global pair list ----
    int E = (int)gE[n]; if (E > ECAP) E = ECAP;
    for (int k = tid; k < E; k += 256) {
        u32 p = gPairs[(size_t)n * ECAP + k];
        atomicAdd(&cnt[p >> 13], 1u);
    }
    __syncthreads();
    // scan: 250 threads x 20 elems + block Hillis-Steele over totals
    u32 s = 0; int base = tid * 20;
    if (tid < 250) for (int q = 0; q < 20; ++q) s += cnt[base + q];
    scanb[tid] = s;
    __syncthreads();
    for (int off = 1; off < 256; off <<= 1) {
        u32 v = (tid >= off) ? scanb[tid - off] : 0;
        __syncthreads();
        scanb[tid] += v;
        __syncthreads();
    }
    u32 tbase = (tid == 0) ? 0u : scanb[tid - 1];
    if (tid < 250) {
        u32 run = tbase;
        for (int q = 0; q < 20; ++q) { offs[base + q] = run; run += cnt[base + q]; }
    }
    if (tid == 0) offs[KTOT] = scanb[255];
    __syncthreads();
    for (int i = tid; i < KTOT; i += 256) cnt[i] = 0;   // reuse as fill cursor
    __syncthreads();
    for (int k = tid; k < E; k += 256) {
        u32 p = gPairs[(size_t)n * ECAP + k];
        u32 src = p >> 13, dst = p & 0x1FFFu;
        u32 slot = offs[src] + atomicAdd(&cnt[src], 1u);
        if (slot < LECAP) edges[slot] = (u16)dst;
        else gEdges[(size_t)n * ECAP + slot] = (u16)dst;
    }
    __syncthreads();

    // ---- wave-0 sweep: rank order, no global memory on the critical path ----
    if (wv == 0) {
        int picks = 0;
        for (int w = 0; w < 79 && picks < 1000; ++w) {
            u64 rw = ((u64)rem32[2 * w + 1] << 32) | rem32[2 * w];
            u64 alive = ~rw;
            if (alive == 0ULL) continue;
            int c = w * 64 + lane;
            bool amAlive = ((alive >> lane) & 1ULL) != 0ULL;
            int e0 = 0, e1 = 0;
            if (amAlive) { e0 = (int)offs[c]; e1 = (int)offs[c + 1]; }
            // intra-word suppression bits (rare)
            colLo[lane] = 0; colHi[lane] = 0;
            bool anyIntra = false;
            for (int k = e0; k < e1; ++k) {
                int dst = (k < LECAP) ? (int)edges[k] : (int)gEdges[(size_t)n * ECAP + k];
                if ((dst >> 6) == w) {
                    if (lane < 32) atomicOr(&colLo[dst & 63], 1u << lane);
                    else           atomicOr(&colHi[dst & 63], 1u << (lane - 32));
                    anyIntra = true;
                }
            }
            u64 cm;
            if (__ballot(anyIntra) == 0ULL) {
                cm = alive;                                   // fast path: no intra-word conflicts
            } else {
                u64 col = ((u64)colHi[lane] << 32) | colLo[lane];
                cm = 0ULL;
                for (int e = 0; e < 64; ++e) {
                    if (!((alive >> e) & 1ULL)) continue;
                    u64 ce = __shfl(col, e);
                    if ((cm & ce) == 0ULL) cm |= (1ULL << e);
                }
            }
            int allowed = 1000 - picks;
            int ncom = __popcll(cm);
            while (ncom > allowed) { cm &= ~(1ULL << (63 - __clzll(cm))); --ncom; }
            // committed lanes: write output + apply forward kills
            if ((cm >> lane) & 1ULL) {
                int pos = picks + (int)__popcll(cm & ((1ULL << lane) - 1ULL));
                const float* bp = &sbox[(size_t)(n * KTOT + c) * 4];
                float* op = &out[(n * 1000 + pos) * 5];
                op[0] = bp[0]; op[1] = bp[1]; op[2] = bp[2]; op[3] = bp[3];
                op[4] = ssc[n * KTOT + c];
                for (int k = e0; k < e1; ++k) {
                    int dst = (k < LECAP) ? (int)edges[k] : (int)gEdges[(size_t)n * ECAP + k];
                    atomicOr(&rem32[dst >> 5], 1u << (dst & 31));
                }
            }
            picks += ncom;
        }
        if (lane == 0) picksS = picks;
    }
    __syncthreads();
    // zero-fill remaining output rows
    int picksF = picksS;
    int basec = (n * 1000 + picksF) * 5, cntz = (1000 - picksF) * 5;
    for (int t = tid; t < cntz; t += 256) out[basec + t] = 0.f;
}

// ---------------- workspace layout ----------------
constexpr size_t OFF_HIST   = 0;                                       // zeroed region start
constexpr size_t OFF_GCNT   = OFF_HIST + 10 * BINS * 4;                // 81920
constexpr size_t OFF_ECNT   = OFF_GCNT + 64;
constexpr size_t OFF_GEC    = OFF_ECNT + 64;                           // edge counters (2 u32)
constexpr size_t ZERO_WORDS = (10 * BINS * 4 + 192) / 4;               // hist + gcnt + ecnt + gec
constexpr size_t OFF_BINB   = OFF_GEC + 64;
constexpr size_t OFF_KNEED  = OFF_BINB + 64;
constexpr size_t OFF_G0     = OFF_KNEED + 64;
constexpr size_t OFF_SEL    = OFF_G0 + 64;
constexpr size_t OFF_EQ     = OFF_SEL + 10 * K_PER_LVL * 4;            // 8-aligned
constexpr size_t OFF_KEY64  = OFF_EQ + (size_t)10 * EQ_CAP * 8;
constexpr size_t OFF_CSC    = OFF_KEY64 + (size_t)NIMG * KTOT * 8;
constexpr size_t OFF_CBOX   = OFF_CSC + (size_t)NIMG * KTOT * 4;
constexpr size_t OFF_COBOX  = OFF_CBOX + (size_t)NIMG * KTOT * 16;
constexpr size_t OFF_SSC    = OFF_COBOX + (size_t)NIMG * KTOT * 16;
constexpr size_t OFF_SBOX   = OFF_SSC + (size_t)NIMG * KTOT * 4;
constexpr size_t OFF_SOBOX  = OFF_SBOX + (size_t)NIMG * KTOT * 16;
constexpr size_t OFF_PAIRS  = OFF_SOBOX + (size_t)NIMG * KTOT * 16;    // u32[NIMG*ECAP]
constexpr size_t OFF_ESPILL = OFF_PAIRS + (size_t)NIMG * ECAP * 4;     // u16[NIMG*ECAP]
constexpr size_t WS_NEEDED  = OFF_ESPILL + (size_t)NIMG * ECAP * 2;    // ~2.3 MB

extern "C" void kernel_launch(void* const* d_in, const int* in_sizes, int n_in,
                              void* d_out, int out_size, void* d_ws, size_t ws_size,
                              hipStream_t stream) {
    if (ws_size < WS_NEEDED) return;

    // Detect input ordering from sizes: dict order interleaves (obj0,box0,...)
    bool dictOrder = (in_sizes[1] > in_sizes[0]);
    Ptrs P;
    for (int l = 0; l < 5; ++l) {
        P.o[l] = (const float*)d_in[dictOrder ? (2 * l)     : l];
        P.b[l] = (const float*)d_in[dictOrder ? (2 * l + 1) : (5 + l)];
    }
    char* ws = (char*)d_ws;
    u32*   hist   = (u32*)(ws + OFF_HIST);
    u32*   gcnt   = (u32*)(ws + OFF_GCNT);
    u32*   ecnt   = (u32*)(ws + OFF_ECNT);
    u32*   gec    = (u32*)(ws + OFF_GEC);
    int*   binB   = (int*)(ws + OFF_BINB);
    int*   kneed  = (int*)(ws + OFF_KNEED);
    int*   g0     = (int*)(ws + OFF_G0);
    int*   sel    = (int*)(ws + OFF_SEL);
    u64*   eq     = (u64*)(ws + OFF_EQ);
    u64*   key64  = (u64*)(ws + OFF_KEY64);
    float* csc    = (float*)(ws + OFF_CSC);
    float* cbox   = (float*)(ws + OFF_CBOX);
    float* cobox  = (float*)(ws + OFF_COBOX);
    float* ssc    = (float*)(ws + OFF_SSC);
    float* sbox   = (float*)(ws + OFF_SBOX);
    float* sobox  = (float*)(ws + OFF_SOBOX);
    u32*   pairs  = (u32*)(ws + OFF_PAIRS);
    u16*   espill = (u16*)(ws + OFF_ESPILL);
    float* out    = (float*)d_out;

    k_zero<<<dim3(21), 256, 0, stream>>>(hist, (int)ZERO_WORDS);       // hist + counters + edge counters
    k_hist<<<dim3(32, 10), 256, 0, stream>>>(P, hist);
    k_resolve<<<10, 256, 0, stream>>>(hist, binB, kneed, g0);
    k_compact<<<dim3(64, 10), 256, 0, stream>>>(P, binB, gcnt, ecnt, sel, eq);
    k_eqsel<<<10, 256, 0, stream>>>(ecnt, kneed, g0, eq, sel);
    k_feat<<<dim3((NIMG * KTOT + 255) / 256), 256, 0, stream>>>(P, sel, key64, csc, cbox, cobox);
    k_rank<<<dim3((KTOT + 255) / 256, NIMG), 1024, 0, stream>>>(key64, csc, cbox, cobox, ssc, sbox, sobox);
    k_edge<<<dim3(79, 79, NIMG), 64, 0, stream>>>(sobox, gec, pairs);
    k_nms<<<NIMG, 256, 0, stream>>>(ssc, sbox, gec, pairs, espill, out);
}

// Round 13
// 234.434 us; speedup vs baseline: 1.2886x; 1.2886x over previous
//
#include <hip/hip_runtime.h>
#include <cmath>

#pragma clang fp contract(off)

typedef unsigned int u32;
typedef unsigned short u16;
typedef unsigned long long u64;

#define K_PER_LVL 1000
#define KTOT 5000            // 5 levels * 1000
#define NIMG 2
#define BINS 2048            // histogram bins = top 11 bits of fkey
#define BIN_SHIFT 21
#define EQ_CAP 2048
#define ECAP 32768           // max suppression edges per image (est ~4k; 8x margin)
#define LECAP 24576          // edges held in LDS; overflow spills to global
#define CBUF 1024            // per-block staging capacity in k_compact
#define RNK_IB 512           // rank: i-candidates per block (2 per thread)
#define RNK_JB 250           // rank: j-keys per block
#define RNK_NJ (KTOT / RNK_JB)   // 20 j-blocks

__constant__ int c_LG[5] = {512, 256, 128, 64, 32};      // grid dim (square)
__constant__ int c_LS[5] = {4, 8, 16, 32, 64};           // stride
__constant__ int c_LZ[5] = {32, 64, 128, 256, 512};      // anchor size
__constant__ int c_LM[5] = {786432, 196608, 49152, 12288, 3072}; // 3*G*G

struct Ptrs { const float* o[5]; const float* b[5]; };

// monotone float -> uint key (larger float => larger key)
__device__ inline u32 fkey(float f) {
    u32 u = __float_as_uint(f);
    return (u & 0x80000000u) ? ~u : (u | 0x80000000u);
}

// ---------------- zero hist + counters ----------------
__global__ __launch_bounds__(256) void k_zero(u32* __restrict__ z, int nwords) {
    int i = blockIdx.x * 256 + threadIdx.x;
    int stride = gridDim.x * 256;
    for (; i < nwords; i += stride) z[i] = 0;
}

// ---------------- one-pass 2048-bin histogram (float4 loads, LDS pre-agg) ----------------
__global__ __launch_bounds__(256) void k_hist(Ptrs P, u32* __restrict__ hist) {
    int p = blockIdx.y; int l = p % 5; int n = p / 5;
    int M4 = c_LM[l] >> 2;
    const float4* base = (const float4*)(P.o[l] + (size_t)n * c_LM[l]);
    __shared__ u32 lh[BINS];
    for (int i = threadIdx.x; i < BINS; i += 256) lh[i] = 0;
    __syncthreads();
    int stride = gridDim.x * 256;
    for (int i = blockIdx.x * 256 + threadIdx.x; i < M4; i += stride) {
        float4 v = base[i];
        atomicAdd(&lh[fkey(v.x) >> BIN_SHIFT], 1u);
        atomicAdd(&lh[fkey(v.y) >> BIN_SHIFT], 1u);
        atomicAdd(&lh[fkey(v.z) >> BIN_SHIFT], 1u);
        atomicAdd(&lh[fkey(v.w) >> BIN_SHIFT], 1u);
    }
    __syncthreads();
    for (int i = threadIdx.x; i < BINS; i += 256) {
        u32 c = lh[i];
        if (c) atomicAdd(&hist[p * BINS + i], c);
    }
}

// ---------------- resolve: threshold bin B, G = #(keys above B), KF = 1000 - G ----------------
__global__ __launch_bounds__(256) void k_resolve(const u32* __restrict__ hist,
                                                 int* __restrict__ binB, int* __restrict__ kneed,
                                                 int* __restrict__ g0) {
    int p = blockIdx.x, t = threadIdx.x;
    __shared__ u32 lh[BINS];
    __shared__ u32 seg[256];
    for (int i = t; i < BINS; i += 256) lh[i] = hist[p * BINS + i];
    __syncthreads();
    u32 s = 0;
    for (int q = 0; q < 8; ++q) s += lh[t * 8 + q];
    seg[t] = s;
    __syncthreads();
    if (t == 0) {
        u32 G = 0; int B = 0;
        for (int sg = 255; sg >= 0; --sg) {
            if (G + seg[sg] >= (u32)K_PER_LVL) {
                for (int b = sg * 8 + 7; b >= sg * 8; --b) {
                    u32 c = lh[b];
                    if (G + c >= (u32)K_PER_LVL) { B = b; break; }
                    G += c;
                }
                break;
            }
            G += seg[sg];
        }
        binB[p] = B;
        kneed[p] = K_PER_LVL - (int)G;   // KF taken from boundary bin
        g0[p] = (int)G;                  // count strictly above bin B
    }
}

// ---------------- compact: block-local LDS staging, ONE reservation atomic per block ----------------
__global__ __launch_bounds__(256) void k_compact(Ptrs P, const int* __restrict__ binB,
                                                 u32* gcnt, u32* ecnt,
                                                 int* __restrict__ sel, u64* __restrict__ eq) {
    int p = blockIdx.y; int l = p % 5; int n = p / 5;
    int M4 = c_LM[l] >> 2; int gg = c_LM[l] / 3;
    const float4* base = (const float4*)(P.o[l] + (size_t)n * c_LM[l]);
    int B = binB[p];
    __shared__ u32 lsel[CBUF];
    __shared__ u64 leq[CBUF];
    __shared__ u32 cSel, cEq, baseSel, baseEq;
    if (threadIdx.x == 0) { cSel = 0; cEq = 0; }
    __syncthreads();
    int stride = gridDim.x * 256;
    for (int i4 = blockIdx.x * 256 + threadIdx.x; i4 < M4; i4 += stride) {
        float4 v = base[i4];
        float vv[4] = {v.x, v.y, v.z, v.w};
        #pragma unroll
        for (int q = 0; q < 4; ++q) {
            u32 k = fkey(vv[q]);
            int bin = (int)(k >> BIN_SHIFT);
            if (bin < B) continue;
            int i = i4 * 4 + q;
            // input linear i = a*gg + pix ; flattened m = pix*3 + a  (h,w,a order)
            int a = i / gg; int pix = i - a * gg; int m = pix * 3 + a;
            if (bin > B) {
                u32 t = atomicAdd(&cSel, 1u);
                if (t < CBUF) lsel[t] = (u32)m;
                else { u32 pos = atomicAdd(&gcnt[p], 1u); sel[p * K_PER_LVL + pos] = m; }
            } else {
                u64 pk = ((u64)k << 20) | (u64)(0xFFFFFu ^ (u32)m);
                u32 t = atomicAdd(&cEq, 1u);
                if (t < CBUF) leq[t] = pk;
                else { u32 e = atomicAdd(&ecnt[p], 1u); if (e < EQ_CAP) eq[(size_t)p * EQ_CAP + e] = pk; }
            }
        }
    }
    __syncthreads();
    if (threadIdx.x == 0) {
        u32 ns = cSel < CBUF ? cSel : CBUF;
        u32 ne = cEq < CBUF ? cEq : CBUF;
        baseSel = ns ? atomicAdd(&gcnt[p], ns) : 0u;
        baseEq  = ne ? atomicAdd(&ecnt[p], ne) : 0u;
    }
    __syncthreads();
    u32 ns = cSel < CBUF ? cSel : CBUF;
    u32 ne = cEq < CBUF ? cEq : CBUF;
    for (u32 i = threadIdx.x; i < ns; i += 256) sel[p * K_PER_LVL + baseSel + i] = (int)lsel[i];
    for (u32 i = threadIdx.x; i < ne; i += 256) {
        u32 slot = baseEq + i;
        if (slot < EQ_CAP) eq[(size_t)p * EQ_CAP + slot] = leq[i];
    }
}

// ---------------- boundary bin: rank-by-count selection (keys unique), take KF lowest ranks ----------------
__global__ __launch_bounds__(256) void k_eqsel(const u32* __restrict__ ecnt, const int* __restrict__ kneed,
                                               const int* __restrict__ g0,
                                               const u64* __restrict__ eq, int* __restrict__ sel) {
    int p = blockIdx.x, t = threadIdx.x;
    int E = (int)ecnt[p]; if (E > EQ_CAP) E = EQ_CAP;
    int KF = kneed[p]; int G0 = g0[p];
    __shared__ u64 a[EQ_CAP];
    for (int i = t; i < E; i += 256) a[i] = eq[(size_t)p * EQ_CAP + i];
    __syncthreads();
    u64 mine[8]; int rk[8];
    #pragma unroll
    for (int q = 0; q < 8; ++q) {
        int i = t + q * 256;
        mine[q] = (i < E) ? a[i] : 0ULL;
        rk[q] = 0;
    }
    for (int j = 0; j < E; ++j) {
        u64 v = a[j];                            // uniform index -> LDS broadcast
        #pragma unroll
        for (int q = 0; q < 8; ++q) rk[q] += (v > mine[q]) ? 1 : 0;
    }
    #pragma unroll
    for (int q = 0; q < 8; ++q) {
        int i = t + q * 256;
        if (i < E && rk[q] < KF) {
            int m = (int)(0xFFFFFu ^ (u32)(mine[q] & 0xFFFFFu));
            sel[p * K_PER_LVL + G0 + rk[q]] = m;
        }
    }
}

// ---------------- featurize: anchors + decode + clip + score + 64b order key ----------------
__global__ void k_feat(Ptrs P, const int* __restrict__ sel, u64* __restrict__ key64,
                       float* __restrict__ csc, float* __restrict__ cbox, float* __restrict__ cobox) {
    int tid = blockIdx.x * 256 + threadIdx.x;
    if (tid >= NIMG * KTOT) return;
    int p = tid / K_PER_LVL, s = tid - p * K_PER_LVL;
    int n = p / 5, l = p % 5;
    int G = c_LG[l], S = c_LS[l], Z = c_LZ[l];
    int gg = G * G;
    int m = sel[p * K_PER_LVL + s];
    int a = m % 3; int pix = m / 3; int h = pix / G; int w = pix - h * G;

    // anchor base: hr=sqrt(ar), wr=1/hr, round-half-even (matches jnp f32)
    const float ars[3] = {0.5f, 1.0f, 2.0f};
    float ar = ars[a];
    float hr = sqrtf(ar), wr = 1.0f / hr;
    float wsz = wr * (float)Z, hsz = hr * (float)Z;
    float bx1 = rintf(-0.5f * wsz), by1 = rintf(-0.5f * hsz);
    float bx2 = rintf(0.5f * wsz),  by2 = rintf(0.5f * hsz);
    float sx = (float)(w * S), sy = (float)(h * S);
    float ax1 = sx + bx1, ay1 = sy + by1, ax2 = sx + bx2, ay2 = sy + by2;
    float wa = ax2 - ax1, ha = ay2 - ay1;
    float cxa = ax1 + 0.5f * wa, cya = ay1 + 0.5f * ha;

    const float* bb = P.b[l] + (size_t)n * 12 * gg;
    float dx = bb[(a * 4 + 0) * gg + pix];
    float dy = bb[(a * 4 + 1) * gg + pix];
    const float CLIPV = 4.135166556742356f;  // log(1000/16)
    float dw = fminf(bb[(a * 4 + 2) * gg + pix], CLIPV);
    float dh = fminf(bb[(a * 4 + 3) * gg + pix], CLIPV);
    float cx = dx * wa + cxa, cy = dy * ha + cya;
    float ww = expf(dw) * wa, hh = expf(dh) * ha;
    float x1 = cx - 0.5f * ww, y1 = cy - 0.5f * hh;
    float x2 = cx + 0.5f * ww, y2 = cy + 0.5f * hh;
    x1 = fminf(fmaxf(x1, 0.f), 2048.f);
    y1 = fminf(fmaxf(y1, 0.f), 2048.f);
    x2 = fminf(fmaxf(x2, 0.f), 2048.f);
    y2 = fminf(fmaxf(y2, 0.f), 2048.f);

    float raw = P.o[l][(size_t)n * 3 * gg + a * gg + pix];
    float sc = 1.0f / (1.0f + expf(-raw));
    bool keep = (x2 - x1 >= 1e-3f) && (y2 - y1 >= 1e-3f) && (sc > 0.0f);

    int slot = n * KTOT + l * K_PER_LVL + s;
    // total order key: raw desc, then (level asc, m asc) == reference concat-position order
    u32 tb = ((u32)l << 20) | (u32)m;          // m < 2^20, l < 8  -> 23 bits, unique
    u32 kk = keep ? fkey(raw) : 0u;            // invalid sinks below every valid (finite raw)
    key64[slot] = ((u64)kk << 23) | (u64)(tb ^ 0x7FFFFFu);

    csc[slot] = keep ? sc : -INFINITY;
    cbox[slot * 4 + 0] = x1; cbox[slot * 4 + 1] = y1;
    cbox[slot * 4 + 2] = x2; cbox[slot * 4 + 3] = y2;
    float off = 4097.0f * (float)l;            // lvl * (W+H+1), batched_nms offset
    cobox[slot * 4 + 0] = x1 + off; cobox[slot * 4 + 1] = y1 + off;
    cobox[slot * 4 + 2] = x2 + off; cobox[slot * 4 + 3] = y2 + off;
}

// ---------------- rank part 1: tiled partial counts (i-block x j-block), no atomics ----------------
// rounds 10-12: single-dispatch rank concentrated 800k wave-DS-insts on 40 CUs
// (~20k/CU -> 56-71 us regardless of pipe). Tiling over (10 i-blk, 20 j-blk, 2)
// = 400 blocks spreads the same compares over all 256 CUs, and each LDS key-read
// serves 2 candidates. Partials are written disjointly; sum in k_scat is exact.
__global__ __launch_bounds__(256) void k_rankp(const u64* __restrict__ key64, u32* __restrict__ rpart) {
    int n = blockIdx.z;
    int i0 = blockIdx.x * RNK_IB;
    int j0 = blockIdx.y * RNK_JB;
    __shared__ u64 kj[RNK_JB];
    const u64* kb = key64 + (size_t)n * KTOT;
    for (int t = threadIdx.x; t < RNK_JB; t += 256) kj[t] = kb[j0 + t];
    __syncthreads();
    int i1 = i0 + threadIdx.x, i2 = i1 + 256;
    u64 k1 = (i1 < KTOT) ? kb[i1] : ~0ULL;
    u64 k2 = (i2 < KTOT) ? kb[i2] : ~0ULL;
    u32 r1 = 0, r2 = 0;
    #pragma unroll 10
    for (int j = 0; j < RNK_JB; ++j) {
        u64 v = kj[j];
        r1 += (v > k1) ? 1u : 0u;
        r2 += (v > k2) ? 1u : 0u;
    }
    u32* rp = rpart + (size_t)blockIdx.y * (NIMG * KTOT) + n * KTOT;
    if (i1 < KTOT) rp[i1] = r1;
    if (i2 < KTOT) rp[i2] = r2;
}

// ---------------- rank part 2: sum partials, scatter payload to sorted slots ----------------
__global__ __launch_bounds__(256) void k_scat(const u32* __restrict__ rpart, const float* __restrict__ csc,
                       const float* __restrict__ cbox, const float* __restrict__ cobox,
                       float* __restrict__ ssc, float* __restrict__ sbox, float* __restrict__ sobox) {
    int n = blockIdx.y;
    int i = blockIdx.x * 256 + threadIdx.x;
    if (i >= KTOT) return;
    int idx = n * KTOT + i;
    u32 rank = 0;
    #pragma unroll
    for (int jb = 0; jb < RNK_NJ; ++jb) rank += rpart[(size_t)jb * (NIMG * KTOT) + idx];
    int src = idx, dst = n * KTOT + (int)rank;
    ssc[dst] = csc[src];
    sbox[dst * 4 + 0] = cbox[src * 4 + 0]; sbox[dst * 4 + 1] = cbox[src * 4 + 1];
    sbox[dst * 4 + 2] = cbox[src * 4 + 2]; sbox[dst * 4 + 3] = cbox[src * 4 + 3];
    sobox[dst * 4 + 0] = cobox[src * 4 + 0]; sobox[dst * 4 + 1] = cobox[src * 4 + 1];
    sobox[dst * 4 + 2] = cobox[src * 4 + 2]; sobox[dst * 4 + 3] = cobox[src * 4 + 3];
}

// ---------------- sparse suppression edges: forward pairs (i<j) with IoU>0.7 ----------------
__global__ void k_edge(const float* __restrict__ sobox, u32* __restrict__ gE, u32* __restrict__ gPairs) {
    int n = blockIdx.z;
    int bi = blockIdx.x, bj = blockIdx.y;
    if (bj < bi) return;                         // forward-only (upper triangle)
    int i = bi * 64 + threadIdx.x;
    int j0 = bj * 64;
    __shared__ float cb[64][4];
    int jl = j0 + threadIdx.x;
    if (jl < KTOT) {
        cb[threadIdx.x][0] = sobox[(size_t)(n * KTOT + jl) * 4 + 0];
        cb[threadIdx.x][1] = sobox[(size_t)(n * KTOT + jl) * 4 + 1];
        cb[threadIdx.x][2] = sobox[(size_t)(n * KTOT + jl) * 4 + 2];
        cb[threadIdx.x][3] = sobox[(size_t)(n * KTOT + jl) * 4 + 3];
    } else {
        cb[threadIdx.x][0] = 0.f; cb[threadIdx.x][1] = 0.f;
        cb[threadIdx.x][2] = 0.f; cb[threadIdx.x][3] = 0.f;
    }
    __syncthreads();
    if (i >= KTOT) return;
    float x1 = sobox[(size_t)(n * KTOT + i) * 4 + 0];
    float y1 = sobox[(size_t)(n * KTOT + i) * 4 + 1];
    float x2 = sobox[(size_t)(n * KTOT + i) * 4 + 2];
    float y2 = sobox[(size_t)(n * KTOT + i) * 4 + 3];
    float areai = fmaxf(x2 - x1, 0.f) * fmaxf(y2 - y1, 0.f);
    int lim = KTOT - j0; if (lim > 64) lim = 64;
    for (int jj = 0; jj < lim; ++jj) {
        int j = j0 + jj;
        if (j <= i) continue;
        float bx1 = cb[jj][0], by1 = cb[jj][1], bx2 = cb[jj][2], by2 = cb[jj][3];
        float areaj = fmaxf(bx2 - bx1, 0.f) * fmaxf(by2 - by1, 0.f);
        float ltx = fmaxf(x1, bx1), lty = fmaxf(y1, by1);
        float rbx = fminf(x2, bx2), rby = fminf(y2, by2);
        float iw = fmaxf(rbx - ltx, 0.f), ih = fmaxf(rby - lty, 0.f);
        float inter = iw * ih;
        float iou = inter / (areai + areaj - inter + 1e-9f);
        if (iou > 0.7f) {
            u32 pos = atomicAdd(&gE[n], 1u);
            if (pos < ECAP) gPairs[(size_t)n * ECAP + pos] = ((u32)i << 13) | (u32)j;
        }
    }
}

// ---------------- greedy NMS sweep over sparse CSR (zero global mem on sweep path) ----------------
__global__ __launch_bounds__(256, 1) void k_nms(const float* __restrict__ ssc,
                      const float* __restrict__ sbox,
                      const u32* __restrict__ gE, const u32* __restrict__ gPairs,
                      u16* __restrict__ gEdges, float* __restrict__ out) {
    int n = blockIdx.x, tid = threadIdx.x;
    int lane = tid & 63, wv = tid >> 6;          // 4 waves
    __shared__ u32 cnt[KTOT];                    // 20 KB (count, then fill cursor)
    __shared__ u32 offs[KTOT + 1];               // 20 KB
    __shared__ u16 edges[LECAP];                 // 48 KB
    __shared__ u32 rem32[160];                   // dead bitmap (2 u32 per 64-word)
    __shared__ u32 colLo[64], colHi[64];
    __shared__ u32 scanb[256];
    __shared__ int picksS;

    // zero cnt + rem tail
    for (int i = tid; i < KTOT; i += 256) cnt[i] = 0;
    if (tid < 160) rem32[tid] = 0xFFFFFFFFu;     // default dead; real words overwritten
    __syncthreads();
    // dead-map init from scores (wave-parallel ballots)
    for (int w = wv; w < 79; w += 4) {
        int i = w * 64 + lane;
        bool dead = (i >= KTOT) || !(ssc[n * KTOT + i] > -INFINITY);
        u64 db = __ballot(dead);
        if (lane == 0) { rem32[2 * w] = (u32)db; rem32[2 * w + 1] = (u32)(db >> 32); }
    }
    __syncthreads();

    // ---- CSR build from global pair list ----
    int E = (int)gE[n]; if (E > ECAP) E = ECAP;
    for (int k = tid; k < E; k += 256) {
        u32 p = gPairs[(size_t)n * ECAP + k];
        atomicAdd(&cnt[p >> 13], 1u);
    }
    __syncthreads();
    // scan: 250 threads x 20 elems + block Hillis-Steele over totals
    u32 s = 0; int base = tid * 20;
    if (tid < 250) for (int q = 0; q < 20; ++q) s += cnt[base + q];
    scanb[tid] = s;
    __syncthreads();
    for (int off = 1; off < 256; off <<= 1) {
        u32 v = (tid >= off) ? scanb[tid - off] : 0;
        __syncthreads();
        scanb[tid] += v;
        __syncthreads();
    }
    u32 tbase = (tid == 0) ? 0u : scanb[tid - 1];
    if (tid < 250) {
        u32 run = tbase;
        for (int q = 0; q < 20; ++q) { offs[base + q] = run; run += cnt[base + q]; }
    }
    if (tid == 0) offs[KTOT] = scanb[255];
    __syncthreads();
    for (int i = tid; i < KTOT; i += 256) cnt[i] = 0;   // reuse as fill cursor
    __syncthreads();
    for (int k = tid; k < E; k += 256) {
        u32 p = gPairs[(size_t)n * ECAP + k];
        u32 src = p >> 13, dst = p & 0x1FFFu;
        u32 slot = offs[src] + atomicAdd(&cnt[src], 1u);
        if (slot < LECAP) edges[slot] = (u16)dst;
        else gEdges[(size_t)n * ECAP + slot] = (u16)dst;
    }
    __syncthreads();

    // ---- wave-0 sweep: rank order, no global memory on the critical path ----
    if (wv == 0) {
        int picks = 0;
        for (int w = 0; w < 79 && picks < 1000; ++w) {
            u64 rw = ((u64)rem32[2 * w + 1] << 32) | rem32[2 * w];
            u64 alive = ~rw;
            if (alive == 0ULL) continue;
            int c = w * 64 + lane;
            bool amAlive = ((alive >> lane) & 1ULL) != 0ULL;
            int e0 = 0, e1 = 0;
            if (amAlive) { e0 = (int)offs[c]; e1 = (int)offs[c + 1]; }
            // intra-word suppression bits (rare)
            colLo[lane] = 0; colHi[lane] = 0;
            bool anyIntra = false;
            for (int k = e0; k < e1; ++k) {
                int dst = (k < LECAP) ? (int)edges[k] : (int)gEdges[(size_t)n * ECAP + k];
                if ((dst >> 6) == w) {
                    if (lane < 32) atomicOr(&colLo[dst & 63], 1u << lane);
                    else           atomicOr(&colHi[dst & 63], 1u << (lane - 32));
                    anyIntra = true;
                }
            }
            u64 cm;
            if (__ballot(anyIntra) == 0ULL) {
                cm = alive;                                   // fast path: no intra-word conflicts
            } else {
                u64 col = ((u64)colHi[lane] << 32) | colLo[lane];
                cm = 0ULL;
                for (int e = 0; e < 64; ++e) {
                    if (!((alive >> e) & 1ULL)) continue;
                    u64 ce = __shfl(col, e);
                    if ((cm & ce) == 0ULL) cm |= (1ULL << e);
                }
            }
            int allowed = 1000 - picks;
            int ncom = __popcll(cm);
            while (ncom > allowed) { cm &= ~(1ULL << (63 - __clzll(cm))); --ncom; }
            // committed lanes: write output + apply forward kills
            if ((cm >> lane) & 1ULL) {
                int pos = picks + (int)__popcll(cm & ((1ULL << lane) - 1ULL));
                const float* bp = &sbox[(size_t)(n * KTOT + c) * 4];
                float* op = &out[(n * 1000 + pos) * 5];
                op[0] = bp[0]; op[1] = bp[1]; op[2] = bp[2]; op[3] = bp[3];
                op[4] = ssc[n * KTOT + c];
                for (int k = e0; k < e1; ++k) {
                    int dst = (k < LECAP) ? (int)edges[k] : (int)gEdges[(size_t)n * ECAP + k];
                    atomicOr(&rem32[dst >> 5], 1u << (dst & 31));
                }
            }
            picks += ncom;
        }
        if (lane == 0) picksS = picks;
    }
    __syncthreads();
    // zero-fill remaining output rows
    int picksF = picksS;
    int basec = (n * 1000 + picksF) * 5, cntz = (1000 - picksF) * 5;
    for (int t = tid; t < cntz; t += 256) out[basec + t] = 0.f;
}

// ---------------- workspace layout ----------------
constexpr size_t OFF_HIST   = 0;                                       // zeroed region start
constexpr size_t OFF_GCNT   = OFF_HIST + 10 * BINS * 4;                // 81920
constexpr size_t OFF_ECNT   = OFF_GCNT + 64;
constexpr size_t OFF_GEC    = OFF_ECNT + 64;                           // edge counters (2 u32)
constexpr size_t ZERO_WORDS = (10 * BINS * 4 + 192) / 4;               // hist + gcnt + ecnt + gec
constexpr size_t OFF_BINB   = OFF_GEC + 64;
constexpr size_t OFF_KNEED  = OFF_BINB + 64;
constexpr size_t OFF_G0     = OFF_KNEED + 64;
constexpr size_t OFF_SEL    = OFF_G0 + 64;
constexpr size_t OFF_EQ     = OFF_SEL + 10 * K_PER_LVL * 4;            // 8-aligned
constexpr size_t OFF_KEY64  = OFF_EQ + (size_t)10 * EQ_CAP * 8;
constexpr size_t OFF_CSC    = OFF_KEY64 + (size_t)NIMG * KTOT * 8;
constexpr size_t OFF_CBOX   = OFF_CSC + (size_t)NIMG * KTOT * 4;
constexpr size_t OFF_COBOX  = OFF_CBOX + (size_t)NIMG * KTOT * 16;
constexpr size_t OFF_SSC    = OFF_COBOX + (size_t)NIMG * KTOT * 16;
constexpr size_t OFF_SBOX   = OFF_SSC + (size_t)NIMG * KTOT * 4;
constexpr size_t OFF_SOBOX  = OFF_SBOX + (size_t)NIMG * KTOT * 16;
constexpr size_t OFF_PAIRS  = OFF_SOBOX + (size_t)NIMG * KTOT * 16;    // u32[NIMG*ECAP]
constexpr size_t OFF_ESPILL = OFF_PAIRS + (size_t)NIMG * ECAP * 4;     // u16[NIMG*ECAP]
constexpr size_t OFF_RPART  = OFF_ESPILL + (size_t)NIMG * ECAP * 2;    // u32[RNK_NJ][NIMG*KTOT]
constexpr size_t WS_NEEDED  = OFF_RPART + (size_t)RNK_NJ * NIMG * KTOT * 4;  // ~3.1 MB

extern "C" void kernel_launch(void* const* d_in, const int* in_sizes, int n_in,
                              void* d_out, int out_size, void* d_ws, size_t ws_size,
                              hipStream_t stream) {
    if (ws_size < WS_NEEDED) return;

    // Detect input ordering from sizes: dict order interleaves (obj0,box0,...)
    bool dictOrder = (in_sizes[1] > in_sizes[0]);
    Ptrs P;
    for (int l = 0; l < 5; ++l) {
        P.o[l] = (const float*)d_in[dictOrder ? (2 * l)     : l];
        P.b[l] = (const float*)d_in[dictOrder ? (2 * l + 1) : (5 + l)];
    }
    char* ws = (char*)d_ws;
    u32*   hist   = (u32*)(ws + OFF_HIST);
    u32*   gcnt   = (u32*)(ws + OFF_GCNT);
    u32*   ecnt   = (u32*)(ws + OFF_ECNT);
    u32*   gec    = (u32*)(ws + OFF_GEC);
    int*   binB   = (int*)(ws + OFF_BINB);
    int*   kneed  = (int*)(ws + OFF_KNEED);
    int*   g0     = (int*)(ws + OFF_G0);
    int*   sel    = (int*)(ws + OFF_SEL);
    u64*   eq     = (u64*)(ws + OFF_EQ);
    u64*   key64  = (u64*)(ws + OFF_KEY64);
    float* csc    = (float*)(ws + OFF_CSC);
    float* cbox   = (float*)(ws + OFF_CBOX);
    float* cobox  = (float*)(ws + OFF_COBOX);
    float* ssc    = (float*)(ws + OFF_SSC);
    float* sbox   = (float*)(ws + OFF_SBOX);
    float* sobox  = (float*)(ws + OFF_SOBOX);
    u32*   pairs  = (u32*)(ws + OFF_PAIRS);
    u16*   espill = (u16*)(ws + OFF_ESPILL);
    u32*   rpart  = (u32*)(ws + OFF_RPART);
    float* out    = (float*)d_out;

    k_zero<<<dim3(21), 256, 0, stream>>>(hist, (int)ZERO_WORDS);       // hist + counters + edge counters
    k_hist<<<dim3(32, 10), 256, 0, stream>>>(P, hist);
    k_resolve<<<10, 256, 0, stream>>>(hist, binB, kneed, g0);
    k_compact<<<dim3(64, 10), 256, 0, stream>>>(P, binB, gcnt, ecnt, sel, eq);
    k_eqsel<<<10, 256, 0, stream>>>(ecnt, kneed, g0, eq, sel);
    k_feat<<<dim3((NIMG * KTOT + 255) / 256), 256, 0, stream>>>(P, sel, key64, csc, cbox, cobox);
    k_rankp<<<dim3((KTOT + RNK_IB - 1) / RNK_IB, RNK_NJ, NIMG), 256, 0, stream>>>(key64, rpart);
    k_scat<<<dim3((KTOT + 255) / 256, NIMG), 256, 0, stream>>>(rpart, csc, cbox, cobox, ssc, sbox, sobox);
    k_edge<<<dim3(79, 79, NIMG), 64, 0, stream>>>(sobox, gec, pairs);
    k_nms<<<NIMG, 256, 0, stream>>>(ssc, sbox, gec, pairs, espill, out);
}

// Round 14
// 204.371 us; speedup vs baseline: 1.4781x; 1.1471x over previous
//
#include <hip/hip_runtime.h>
#include <cmath>

#pragma clang fp contract(off)

typedef unsigned int u32;
typedef unsigned short u16;
typedef unsigned long long u64;

#define K_PER_LVL 1000
#define KTOT 5000            // 5 levels * 1000
#define NIMG 2
#define BINS 16384           // histogram bins = top 14 bits of fkey (binade/32)
#define BIN_SHIFT 18
#define SEGW (BINS / 256)    // 64 bins per resolve segment
#define EQ_CAP 2048
#define ECAP 32768           // max suppression edges per image (est ~4k; 8x margin)
#define LECAP 24576          // edges held in LDS; overflow spills to global
#define CBUF 1024            // per-block staging capacity in k_compact
#define RNK_IB 512           // rank: i-candidates per block (2 per thread)
#define RNK_JB 250           // rank: j-keys per block
#define RNK_NJ (KTOT / RNK_JB)   // 20 j-blocks

__constant__ int c_LG[5] = {512, 256, 128, 64, 32};      // grid dim (square)
__constant__ int c_LS[5] = {4, 8, 16, 32, 64};           // stride
__constant__ int c_LZ[5] = {32, 64, 128, 256, 512};      // anchor size
__constant__ int c_LM[5] = {786432, 196608, 49152, 12288, 3072}; // 3*G*G

struct Ptrs { const float* o[5]; const float* b[5]; };

// monotone float -> uint key (larger float => larger key)
__device__ inline u32 fkey(float f) {
    u32 u = __float_as_uint(f);
    return (u & 0x80000000u) ? ~u : (u | 0x80000000u);
}

// ---------------- zero hist + counters ----------------
__global__ __launch_bounds__(256) void k_zero(u32* __restrict__ z, int nwords) {
    int i = blockIdx.x * 256 + threadIdx.x;
    int stride = gridDim.x * 256;
    for (; i < nwords; i += stride) z[i] = 0;
}

// ---------------- one-pass 16384-bin histogram (float4 loads, LDS pre-agg) ----------------
// finer bins (binade/32): boundary-bin population E ~110 instead of ~880, which
// is what made round-13's k_eqsel 53 us (E uniform ds_reads x 4 waves on 1 CU).
__global__ __launch_bounds__(256) void k_hist(Ptrs P, u32* __restrict__ hist) {
    int p = blockIdx.y; int l = p % 5; int n = p / 5;
    int M4 = c_LM[l] >> 2;
    const float4* base = (const float4*)(P.o[l] + (size_t)n * c_LM[l]);
    __shared__ u32 lh[BINS];                     // 64 KB
    for (int i = threadIdx.x; i < BINS; i += 256) lh[i] = 0;
    __syncthreads();
    int stride = gridDim.x * 256;
    for (int i = blockIdx.x * 256 + threadIdx.x; i < M4; i += stride) {
        float4 v = base[i];
        atomicAdd(&lh[fkey(v.x) >> BIN_SHIFT], 1u);
        atomicAdd(&lh[fkey(v.y) >> BIN_SHIFT], 1u);
        atomicAdd(&lh[fkey(v.z) >> BIN_SHIFT], 1u);
        atomicAdd(&lh[fkey(v.w) >> BIN_SHIFT], 1u);
    }
    __syncthreads();
    for (int i = threadIdx.x; i < BINS; i += 256) {
        u32 c = lh[i];
        if (c) atomicAdd(&hist[p * BINS + i], c);
    }
}

// ---------------- resolve: threshold bin B, G = #(keys above B), KF = 1000 - G ----------------
// 2-level: parallel 64-bin segment sums -> serial segment walk -> staged 64-bin tail walk.
__global__ __launch_bounds__(256) void k_resolve(const u32* __restrict__ hist,
                                                 int* __restrict__ binB, int* __restrict__ kneed,
                                                 int* __restrict__ g0) {
    int p = blockIdx.x, t = threadIdx.x;
    __shared__ u32 seg[256];
    __shared__ u32 tail[SEGW];
    __shared__ int sgS; __shared__ u32 GS;
    u32 s = 0;
    const u32* hb = hist + p * BINS;
    int base = t * SEGW;
    for (int q = 0; q < SEGW; ++q) s += hb[base + q];
    seg[t] = s;
    __syncthreads();
    if (t == 0) {
        u32 G = 0; int sg = 255;
        for (; sg > 0; --sg) {
            if (G + seg[sg] >= (u32)K_PER_LVL) break;
            G += seg[sg];
        }
        sgS = sg; GS = G;
    }
    __syncthreads();
    int sg = sgS;
    if (t < SEGW) tail[t] = hb[sg * SEGW + t];
    __syncthreads();
    if (t == 0) {
        u32 G = GS; int B = sg * SEGW;
        for (int b = SEGW - 1; b >= 0; --b) {
            u32 c = tail[b];
            if (G + c >= (u32)K_PER_LVL) { B = sg * SEGW + b; break; }
            G += c;
        }
        binB[p] = B;
        kneed[p] = K_PER_LVL - (int)G;   // KF taken from boundary bin
        g0[p] = (int)G;                  // count strictly above bin B
    }
}

// ---------------- compact: block-local LDS staging, ONE reservation atomic per block ----------------
__global__ __launch_bounds__(256) void k_compact(Ptrs P, const int* __restrict__ binB,
                                                 u32* gcnt, u32* ecnt,
                                                 int* __restrict__ sel, u64* __restrict__ eq) {
    int p = blockIdx.y; int l = p % 5; int n = p / 5;
    int M4 = c_LM[l] >> 2; int gg = c_LM[l] / 3;
    const float4* base = (const float4*)(P.o[l] + (size_t)n * c_LM[l]);
    int B = binB[p];
    __shared__ u32 lsel[CBUF];
    __shared__ u64 leq[CBUF];
    __shared__ u32 cSel, cEq, baseSel, baseEq;
    if (threadIdx.x == 0) { cSel = 0; cEq = 0; }
    __syncthreads();
    int stride = gridDim.x * 256;
    for (int i4 = blockIdx.x * 256 + threadIdx.x; i4 < M4; i4 += stride) {
        float4 v = base[i4];
        float vv[4] = {v.x, v.y, v.z, v.w};
        #pragma unroll
        for (int q = 0; q < 4; ++q) {
            u32 k = fkey(vv[q]);
            int bin = (int)(k >> BIN_SHIFT);
            if (bin < B) continue;
            int i = i4 * 4 + q;
            // input linear i = a*gg + pix ; flattened m = pix*3 + a  (h,w,a order)
            int a = i / gg; int pix = i - a * gg; int m = pix * 3 + a;
            if (bin > B) {
                u32 t = atomicAdd(&cSel, 1u);
                if (t < CBUF) lsel[t] = (u32)m;
                else { u32 pos = atomicAdd(&gcnt[p], 1u); sel[p * K_PER_LVL + pos] = m; }
            } else {
                u64 pk = ((u64)k << 20) | (u64)(0xFFFFFu ^ (u32)m);
                u32 t = atomicAdd(&cEq, 1u);
                if (t < CBUF) leq[t] = pk;
                else { u32 e = atomicAdd(&ecnt[p], 1u); if (e < EQ_CAP) eq[(size_t)p * EQ_CAP + e] = pk; }
            }
        }
    }
    __syncthreads();
    if (threadIdx.x == 0) {
        u32 ns = cSel < CBUF ? cSel : CBUF;
        u32 ne = cEq < CBUF ? cEq : CBUF;
        baseSel = ns ? atomicAdd(&gcnt[p], ns) : 0u;
        baseEq  = ne ? atomicAdd(&ecnt[p], ne) : 0u;
    }
    __syncthreads();
    u32 ns = cSel < CBUF ? cSel : CBUF;
    u32 ne = cEq < CBUF ? cEq : CBUF;
    for (u32 i = threadIdx.x; i < ns; i += 256) sel[p * K_PER_LVL + baseSel + i] = (int)lsel[i];
    for (u32 i = threadIdx.x; i < ne; i += 256) {
        u32 slot = baseEq + i;
        if (slot < EQ_CAP) eq[(size_t)p * EQ_CAP + slot] = leq[i];
    }
}

// ---------------- boundary bin: rank-by-count selection (keys unique), take KF lowest ranks ----------------
__global__ __launch_bounds__(256) void k_eqsel(const u32* __restrict__ ecnt, const int* __restrict__ kneed,
                                               const int* __restrict__ g0,
                                               const u64* __restrict__ eq, int* __restrict__ sel) {
    int p = blockIdx.x, t = threadIdx.x;
    int E = (int)ecnt[p]; if (E > EQ_CAP) E = EQ_CAP;
    int KF = kneed[p]; int G0 = g0[p];
    __shared__ u64 a[EQ_CAP];
    for (int i = t; i < E; i += 256) a[i] = eq[(size_t)p * EQ_CAP + i];
    __syncthreads();
    u64 mine[8]; int rk[8];
    #pragma unroll
    for (int q = 0; q < 8; ++q) {
        int i = t + q * 256;
        mine[q] = (i < E) ? a[i] : 0ULL;
        rk[q] = 0;
    }
    for (int j = 0; j < E; ++j) {
        u64 v = a[j];                            // uniform index -> LDS broadcast
        #pragma unroll
        for (int q = 0; q < 8; ++q) rk[q] += (v > mine[q]) ? 1 : 0;
    }
    #pragma unroll
    for (int q = 0; q < 8; ++q) {
        int i = t + q * 256;
        if (i < E && rk[q] < KF) {
            int m = (int)(0xFFFFFu ^ (u32)(mine[q] & 0xFFFFFu));
            sel[p * K_PER_LVL + G0 + rk[q]] = m;
        }
    }
}

// ---------------- featurize: anchors + decode + clip + score + 64b order key ----------------
__global__ void k_feat(Ptrs P, const int* __restrict__ sel, u64* __restrict__ key64,
                       float* __restrict__ csc, float* __restrict__ cbox, float* __restrict__ cobox) {
    int tid = blockIdx.x * 256 + threadIdx.x;
    if (tid >= NIMG * KTOT) return;
    int p = tid / K_PER_LVL, s = tid - p * K_PER_LVL;
    int n = p / 5, l = p % 5;
    int G = c_LG[l], S = c_LS[l], Z = c_LZ[l];
    int gg = G * G;
    int m = sel[p * K_PER_LVL + s];
    int a = m % 3; int pix = m / 3; int h = pix / G; int w = pix - h * G;

    // anchor base: hr=sqrt(ar), wr=1/hr, round-half-even (matches jnp f32)
    const float ars[3] = {0.5f, 1.0f, 2.0f};
    float ar = ars[a];
    float hr = sqrtf(ar), wr = 1.0f / hr;
    float wsz = wr * (float)Z, hsz = hr * (float)Z;
    float bx1 = rintf(-0.5f * wsz), by1 = rintf(-0.5f * hsz);
    float bx2 = rintf(0.5f * wsz),  by2 = rintf(0.5f * hsz);
    float sx = (float)(w * S), sy = (float)(h * S);
    float ax1 = sx + bx1, ay1 = sy + by1, ax2 = sx + bx2, ay2 = sy + by2;
    float wa = ax2 - ax1, ha = ay2 - ay1;
    float cxa = ax1 + 0.5f * wa, cya = ay1 + 0.5f * ha;

    const float* bb = P.b[l] + (size_t)n * 12 * gg;
    float dx = bb[(a * 4 + 0) * gg + pix];
    float dy = bb[(a * 4 + 1) * gg + pix];
    const float CLIPV = 4.135166556742356f;  // log(1000/16)
    float dw = fminf(bb[(a * 4 + 2) * gg + pix], CLIPV);
    float dh = fminf(bb[(a * 4 + 3) * gg + pix], CLIPV);
    float cx = dx * wa + cxa, cy = dy * ha + cya;
    float ww = expf(dw) * wa, hh = expf(dh) * ha;
    float x1 = cx - 0.5f * ww, y1 = cy - 0.5f * hh;
    float x2 = cx + 0.5f * ww, y2 = cy + 0.5f * hh;
    x1 = fminf(fmaxf(x1, 0.f), 2048.f);
    y1 = fminf(fmaxf(y1, 0.f), 2048.f);
    x2 = fminf(fmaxf(x2, 0.f), 2048.f);
    y2 = fminf(fmaxf(y2, 0.f), 2048.f);

    float raw = P.o[l][(size_t)n * 3 * gg + a * gg + pix];
    float sc = 1.0f / (1.0f + expf(-raw));
    bool keep = (x2 - x1 >= 1e-3f) && (y2 - y1 >= 1e-3f) && (sc > 0.0f);

    int slot = n * KTOT + l * K_PER_LVL + s;
    // total order key: raw desc, then (level asc, m asc) == reference concat-position order
    u32 tb = ((u32)l << 20) | (u32)m;          // m < 2^20, l < 8  -> 23 bits, unique
    u32 kk = keep ? fkey(raw) : 0u;            // invalid sinks below every valid (finite raw)
    key64[slot] = ((u64)kk << 23) | (u64)(tb ^ 0x7FFFFFu);

    csc[slot] = keep ? sc : -INFINITY;
    cbox[slot * 4 + 0] = x1; cbox[slot * 4 + 1] = y1;
    cbox[slot * 4 + 2] = x2; cbox[slot * 4 + 3] = y2;
    float off = 4097.0f * (float)l;            // lvl * (W+H+1), batched_nms offset
    cobox[slot * 4 + 0] = x1 + off; cobox[slot * 4 + 1] = y1 + off;
    cobox[slot * 4 + 2] = x2 + off; cobox[slot * 4 + 3] = y2 + off;
}

// ---------------- rank part 1: tiled partial counts (i-block x j-block), no atomics ----------------
__global__ __launch_bounds__(256) void k_rankp(const u64* __restrict__ key64, u32* __restrict__ rpart) {
    int n = blockIdx.z;
    int i0 = blockIdx.x * RNK_IB;
    int j0 = blockIdx.y * RNK_JB;
    __shared__ u64 kj[RNK_JB];
    const u64* kb = key64 + (size_t)n * KTOT;
    for (int t = threadIdx.x; t < RNK_JB; t += 256) kj[t] = kb[j0 + t];
    __syncthreads();
    int i1 = i0 + threadIdx.x, i2 = i1 + 256;
    u64 k1 = (i1 < KTOT) ? kb[i1] : ~0ULL;
    u64 k2 = (i2 < KTOT) ? kb[i2] : ~0ULL;
    u32 r1 = 0, r2 = 0;
    #pragma unroll 10
    for (int j = 0; j < RNK_JB; ++j) {
        u64 v = kj[j];
        r1 += (v > k1) ? 1u : 0u;
        r2 += (v > k2) ? 1u : 0u;
    }
    u32* rp = rpart + (size_t)blockIdx.y * (NIMG * KTOT) + n * KTOT;
    if (i1 < KTOT) rp[i1] = r1;
    if (i2 < KTOT) rp[i2] = r2;
}

// ---------------- rank part 2: sum partials, scatter payload to sorted slots ----------------
__global__ __launch_bounds__(256) void k_scat(const u32* __restrict__ rpart, const float* __restrict__ csc,
                       const float* __restrict__ cbox, const float* __restrict__ cobox,
                       float* __restrict__ ssc, float* __restrict__ sbox, float* __restrict__ sobox) {
    int n = blockIdx.y;
    int i = blockIdx.x * 256 + threadIdx.x;
    if (i >= KTOT) return;
    int idx = n * KTOT + i;
    u32 rank = 0;
    #pragma unroll
    for (int jb = 0; jb < RNK_NJ; ++jb) rank += rpart[(size_t)jb * (NIMG * KTOT) + idx];
    int src = idx, dst = n * KTOT + (int)rank;
    ssc[dst] = csc[src];
    sbox[dst * 4 + 0] = cbox[src * 4 + 0]; sbox[dst * 4 + 1] = cbox[src * 4 + 1];
    sbox[dst * 4 + 2] = cbox[src * 4 + 2]; sbox[dst * 4 + 3] = cbox[src * 4 + 3];
    sobox[dst * 4 + 0] = cobox[src * 4 + 0]; sobox[dst * 4 + 1] = cobox[src * 4 + 1];
    sobox[dst * 4 + 2] = cobox[src * 4 + 2]; sobox[dst * 4 + 3] = cobox[src * 4 + 3];
}

// ---------------- sparse suppression edges: forward pairs (i<j) with IoU>0.7 ----------------
__global__ void k_edge(const float* __restrict__ sobox, u32* __restrict__ gE, u32* __restrict__ gPairs) {
    int n = blockIdx.z;
    int bi = blockIdx.x, bj = blockIdx.y;
    if (bj < bi) return;                         // forward-only (upper triangle)
    int i = bi * 64 + threadIdx.x;
    int j0 = bj * 64;
    __shared__ float cb[64][4];
    int jl = j0 + threadIdx.x;
    if (jl < KTOT) {
        cb[threadIdx.x][0] = sobox[(size_t)(n * KTOT + jl) * 4 + 0];
        cb[threadIdx.x][1] = sobox[(size_t)(n * KTOT + jl) * 4 + 1];
        cb[threadIdx.x][2] = sobox[(size_t)(n * KTOT + jl) * 4 + 2];
        cb[threadIdx.x][3] = sobox[(size_t)(n * KTOT + jl) * 4 + 3];
    } else {
        cb[threadIdx.x][0] = 0.f; cb[threadIdx.x][1] = 0.f;
        cb[threadIdx.x][2] = 0.f; cb[threadIdx.x][3] = 0.f;
    }
    __syncthreads();
    if (i >= KTOT) return;
    float x1 = sobox[(size_t)(n * KTOT + i) * 4 + 0];
    float y1 = sobox[(size_t)(n * KTOT + i) * 4 + 1];
    float x2 = sobox[(size_t)(n * KTOT + i) * 4 + 2];
    float y2 = sobox[(size_t)(n * KTOT + i) * 4 + 3];
    float areai = fmaxf(x2 - x1, 0.f) * fmaxf(y2 - y1, 0.f);
    int lim = KTOT - j0; if (lim > 64) lim = 64;
    for (int jj = 0; jj < lim; ++jj) {
        int j = j0 + jj;
        if (j <= i) continue;
        float bx1 = cb[jj][0], by1 = cb[jj][1], bx2 = cb[jj][2], by2 = cb[jj][3];
        float areaj = fmaxf(bx2 - bx1, 0.f) * fmaxf(by2 - by1, 0.f);
        float ltx = fmaxf(x1, bx1), lty = fmaxf(y1, by1);
        float rbx = fminf(x2, bx2), rby = fminf(y2, by2);
        float iw = fmaxf(rbx - ltx, 0.f), ih = fmaxf(rby - lty, 0.f);
        float inter = iw * ih;
        float iou = inter / (areai + areaj - inter + 1e-9f);
        if (iou > 0.7f) {
            u32 pos = atomicAdd(&gE[n], 1u);
            if (pos < ECAP) gPairs[(size_t)n * ECAP + pos] = ((u32)i << 13) | (u32)j;
        }
    }
}

// ---------------- greedy NMS sweep over sparse CSR (zero global mem on sweep path) ----------------
__global__ __launch_bounds__(256, 1) void k_nms(const float* __restrict__ ssc,
                      const float* __restrict__ sbox,
                      const u32* __restrict__ gE, const u32* __restrict__ gPairs,
                      u16* __restrict__ gEdges, float* __restrict__ out) {
    int n = blockIdx.x, tid = threadIdx.x;
    int lane = tid & 63, wv = tid >> 6;          // 4 waves
    __shared__ u32 cnt[KTOT];                    // 20 KB (count, then fill cursor)
    __shared__ u32 offs[KTOT + 1];               // 20 KB
    __shared__ u16 edges[LECAP];                 // 48 KB
    __shared__ u32 rem32[160];                   // dead bitmap (2 u32 per 64-word)
    __shared__ u32 colLo[64], colHi[64];
    __shared__ u32 scanb[256];
    __shared__ int picksS;

    // zero cnt + rem tail
    for (int i = tid; i < KTOT; i += 256) cnt[i] = 0;
    if (tid < 160) rem32[tid] = 0xFFFFFFFFu;     // default dead; real words overwritten
    __syncthreads();
    // dead-map init from scores (wave-parallel ballots)
    for (int w = wv; w < 79; w += 4) {
        int i = w * 64 + lane;
        bool dead = (i >= KTOT) || !(ssc[n * KTOT + i] > -INFINITY);
        u64 db = __ballot(dead);
        if (lane == 0) { rem32[2 * w] = (u32)db; rem32[2 * w + 1] = (u32)(db >> 32); }
    }
    __syncthreads();

    // ---- CSR build from global pair list ----
    int E = (int)gE[n]; if (E > ECAP) E = ECAP;
    for (int k = tid; k < E; k += 256) {
        u32 p = gPairs[(size_t)n * ECAP + k];
        atomicAdd(&cnt[p >> 13], 1u);
    }
    __syncthreads();
    // scan: 250 threads x 20 elems + block Hillis-Steele over totals
    u32 s = 0; int base = tid * 20;
    if (tid < 250) for (int q = 0; q < 20; ++q) s += cnt[base + q];
    scanb[tid] = s;
    __syncthreads();
    for (int off = 1; off < 256; off <<= 1) {
        u32 v = (tid >= off) ? scanb[tid - off] : 0;
        __syncthreads();
        scanb[tid] += v;
        __syncthreads();
    }
    u32 tbase = (tid == 0) ? 0u : scanb[tid - 1];
    if (tid < 250) {
        u32 run = tbase;
        for (int q = 0; q < 20; ++q) { offs[base + q] = run; run += cnt[base + q]; }
    }
    if (tid == 0) offs[KTOT] = scanb[255];
    __syncthreads();
    for (int i = tid; i < KTOT; i += 256) cnt[i] = 0;   // reuse as fill cursor
    __syncthreads();
    for (int k = tid; k < E; k += 256) {
        u32 p = gPairs[(size_t)n * ECAP + k];
        u32 src = p >> 13, dst = p & 0x1FFFu;
        u32 slot = offs[src] + atomicAdd(&cnt[src], 1u);
        if (slot < LECAP) edges[slot] = (u16)dst;
        else gEdges[(size_t)n * ECAP + slot] = (u16)dst;
    }
    __syncthreads();

    // ---- wave-0 sweep: rank order, no global memory on the critical path ----
    if (wv == 0) {
        int picks = 0;
        for (int w = 0; w < 79 && picks < 1000; ++w) {
            u64 rw = ((u64)rem32[2 * w + 1] << 32) | rem32[2 * w];
            u64 alive = ~rw;
            if (alive == 0ULL) continue;
            int c = w * 64 + lane;
            bool amAlive = ((alive >> lane) & 1ULL) != 0ULL;
            int e0 = 0, e1 = 0;
            if (amAlive) { e0 = (int)offs[c]; e1 = (int)offs[c + 1]; }
            // intra-word suppression bits (rare)
            colLo[lane] = 0; colHi[lane] = 0;
            bool anyIntra = false;
            for (int k = e0; k < e1; ++k) {
                int dst = (k < LECAP) ? (int)edges[k] : (int)gEdges[(size_t)n * ECAP + k];
                if ((dst >> 6) == w) {
                    if (lane < 32) atomicOr(&colLo[dst & 63], 1u << lane);
                    else           atomicOr(&colHi[dst & 63], 1u << (lane - 32));
                    anyIntra = true;
                }
            }
            u64 cm;
            if (__ballot(anyIntra) == 0ULL) {
                cm = alive;                                   // fast path: no intra-word conflicts
            } else {
                u64 col = ((u64)colHi[lane] << 32) | colLo[lane];
                cm = 0ULL;
                for (int e = 0; e < 64; ++e) {
                    if (!((alive >> e) & 1ULL)) continue;
                    u64 ce = __shfl(col, e);
                    if ((cm & ce) == 0ULL) cm |= (1ULL << e);
                }
            }
            int allowed = 1000 - picks;
            int ncom = __popcll(cm);
            while (ncom > allowed) { cm &= ~(1ULL << (63 - __clzll(cm))); --ncom; }
            // committed lanes: write output + apply forward kills
            if ((cm >> lane) & 1ULL) {
                int pos = picks + (int)__popcll(cm & ((1ULL << lane) - 1ULL));
                const float* bp = &sbox[(size_t)(n * KTOT + c) * 4];
                float* op = &out[(n * 1000 + pos) * 5];
                op[0] = bp[0]; op[1] = bp[1]; op[2] = bp[2]; op[3] = bp[3];
                op[4] = ssc[n * KTOT + c];
                for (int k = e0; k < e1; ++k) {
                    int dst = (k < LECAP) ? (int)edges[k] : (int)gEdges[(size_t)n * ECAP + k];
                    atomicOr(&rem32[dst >> 5], 1u << (dst & 31));
                }
            }
            picks += ncom;
        }
        if (lane == 0) picksS = picks;
    }
    __syncthreads();
    // zero-fill remaining output rows
    int picksF = picksS;
    int basec = (n * 1000 + picksF) * 5, cntz = (1000 - picksF) * 5;
    for (int t = tid; t < cntz; t += 256) out[basec + t] = 0.f;
}

// ---------------- workspace layout ----------------
constexpr size_t OFF_HIST   = 0;                                       // zeroed region start
constexpr size_t OFF_GCNT   = OFF_HIST + 10 * BINS * 4;
constexpr size_t OFF_ECNT   = OFF_GCNT + 64;
constexpr size_t OFF_GEC    = OFF_ECNT + 64;                           // edge counters (2 u32)
constexpr size_t ZERO_WORDS = (10 * BINS * 4 + 192) / 4;               // hist + gcnt + ecnt + gec
constexpr size_t OFF_BINB   = OFF_GEC + 64;
constexpr size_t OFF_KNEED  = OFF_BINB + 64;
constexpr size_t OFF_G0     = OFF_KNEED + 64;
constexpr size_t OFF_SEL    = OFF_G0 + 64;
constexpr size_t OFF_EQ     = OFF_SEL + 10 * K_PER_LVL * 4;            // 8-aligned
constexpr size_t OFF_KEY64  = OFF_EQ + (size_t)10 * EQ_CAP * 8;
constexpr size_t OFF_CSC    = OFF_KEY64 + (size_t)NIMG * KTOT * 8;
constexpr size_t OFF_CBOX   = OFF_CSC + (size_t)NIMG * KTOT * 4;
constexpr size_t OFF_COBOX  = OFF_CBOX + (size_t)NIMG * KTOT * 16;
constexpr size_t OFF_SSC    = OFF_COBOX + (size_t)NIMG * KTOT * 16;
constexpr size_t OFF_SBOX   = OFF_SSC + (size_t)NIMG * KTOT * 4;
constexpr size_t OFF_SOBOX  = OFF_SBOX + (size_t)NIMG * KTOT * 16;
constexpr size_t OFF_PAIRS  = OFF_SOBOX + (size_t)NIMG * KTOT * 16;    // u32[NIMG*ECAP]
constexpr size_t OFF_ESPILL = OFF_PAIRS + (size_t)NIMG * ECAP * 4;     // u16[NIMG*ECAP]
constexpr size_t OFF_RPART  = OFF_ESPILL + (size_t)NIMG * ECAP * 2;    // u32[RNK_NJ][NIMG*KTOT]
constexpr size_t WS_NEEDED  = OFF_RPART + (size_t)RNK_NJ * NIMG * KTOT * 4;  // ~3.7 MB

extern "C" void kernel_launch(void* const* d_in, const int* in_sizes, int n_in,
                              void* d_out, int out_size, void* d_ws, size_t ws_size,
                              hipStream_t stream) {
    if (ws_size < WS_NEEDED) return;

    // Detect input ordering from sizes: dict order interleaves (obj0,box0,...)
    bool dictOrder = (in_sizes[1] > in_sizes[0]);
    Ptrs P;
    for (int l = 0; l < 5; ++l) {
        P.o[l] = (const float*)d_in[dictOrder ? (2 * l)     : l];
        P.b[l] = (const float*)d_in[dictOrder ? (2 * l + 1) : (5 + l)];
    }
    char* ws = (char*)d_ws;
    u32*   hist   = (u32*)(ws + OFF_HIST);
    u32*   gcnt   = (u32*)(ws + OFF_GCNT);
    u32*   ecnt   = (u32*)(ws + OFF_ECNT);
    u32*   gec    = (u32*)(ws + OFF_GEC);
    int*   binB   = (int*)(ws + OFF_BINB);
    int*   kneed  = (int*)(ws + OFF_KNEED);
    int*   g0     = (int*)(ws + OFF_G0);
    int*   sel    = (int*)(ws + OFF_SEL);
    u64*   eq     = (u64*)(ws + OFF_EQ);
    u64*   key64  = (u64*)(ws + OFF_KEY64);
    float* csc    = (float*)(ws + OFF_CSC);
    float* cbox   = (float*)(ws + OFF_CBOX);
    float* cobox  = (float*)(ws + OFF_COBOX);
    float* ssc    = (float*)(ws + OFF_SSC);
    float* sbox   = (float*)(ws + OFF_SBOX);
    float* sobox  = (float*)(ws + OFF_SOBOX);
    u32*   pairs  = (u32*)(ws + OFF_PAIRS);
    u16*   espill = (u16*)(ws + OFF_ESPILL);
    u32*   rpart  = (u32*)(ws + OFF_RPART);
    float* out    = (float*)d_out;

    k_zero<<<dim3(64), 256, 0, stream>>>(hist, (int)ZERO_WORDS);       // hist + counters + edge counters
    k_hist<<<dim3(32, 10), 256, 0, stream>>>(P, hist);
    k_resolve<<<10, 256, 0, stream>>>(hist, binB, kneed, g0);
    k_compact<<<dim3(64, 10), 256, 0, stream>>>(P, binB, gcnt, ecnt, sel, eq);
    k_eqsel<<<10, 256, 0, stream>>>(ecnt, kneed, g0, eq, sel);
    k_feat<<<dim3((NIMG * KTOT + 255) / 256), 256, 0, stream>>>(P, sel, key64, csc, cbox, cobox);
    k_rankp<<<dim3((KTOT + RNK_IB - 1) / RNK_IB, RNK_NJ, NIMG), 256, 0, stream>>>(key64, rpart);
    k_scat<<<dim3((KTOT + 255) / 256, NIMG), 256, 0, stream>>>(rpart, csc, cbox, cobox, ssc, sbox, sobox);
    k_edge<<<dim3(79, 79, NIMG), 64, 0, stream>>>(sobox, gec, pairs);
    k_nms<<<NIMG, 256, 0, stream>>>(ssc, sbox, gec, pairs, espill, out);
}

// Round 15
// 198.305 us; speedup vs baseline: 1.5233x; 1.0306x over previous
//
#include <hip/hip_runtime.h>
#include <cmath>

#pragma clang fp contract(off)

typedef unsigned int u32;
typedef unsigned short u16;
typedef unsigned long long u64;

#define K_PER_LVL 1000
#define KTOT 5000            // 5 levels * 1000
#define NIMG 2
#define BINS 16384           // histogram bins = top 14 bits of fkey (binade/32)
#define BIN_SHIFT 18
#define SEGW (BINS / 256)    // 64 bins per resolve segment
#define EQ_CAP 2048
#define ECAP 32768           // max suppression edges per image (est ~4k; 8x margin)
#define LECAP 24576          // edges held in LDS; overflow spills to global
#define CBUF 1024            // per-block staging capacity in k_compact
#define RNK_IB 512           // rank: i-candidates per block (2 per thread)
#define RNK_JB 250           // rank: j-keys per block
#define RNK_NJ (KTOT / RNK_JB)   // 20 j-blocks
#define RNK_TILES 200        // 10 i-blk * 20 j-blk
#define EDGE_TILES 820       // sum_{bi=0..19} (79 - 4*bi)

__constant__ int c_LG[5] = {512, 256, 128, 64, 32};      // grid dim (square)
__constant__ int c_LS[5] = {4, 8, 16, 32, 64};           // stride
__constant__ int c_LZ[5] = {32, 64, 128, 256, 512};      // anchor size
__constant__ int c_LM[5] = {786432, 196608, 49152, 12288, 3072}; // 3*G*G

struct Ptrs { const float* o[5]; const float* b[5]; };

// monotone float -> uint key (larger float => larger key)
__device__ inline u32 fkey(float f) {
    u32 u = __float_as_uint(f);
    return (u & 0x80000000u) ? ~u : (u | 0x80000000u);
}

// ---------------- zero hist + counters ----------------
__global__ __launch_bounds__(256) void k_zero(u32* __restrict__ z, int nwords) {
    int i = blockIdx.x * 256 + threadIdx.x;
    int stride = gridDim.x * 256;
    for (; i < nwords; i += stride) z[i] = 0;
}

// ---------------- one-pass 16384-bin histogram (float4 loads, LDS pre-agg) ----------------
__global__ __launch_bounds__(256) void k_hist(Ptrs P, u32* __restrict__ hist) {
    int p = blockIdx.y; int l = p % 5; int n = p / 5;
    int M4 = c_LM[l] >> 2;
    const float4* base = (const float4*)(P.o[l] + (size_t)n * c_LM[l]);
    __shared__ u32 lh[BINS];                     // 64 KB
    for (int i = threadIdx.x; i < BINS; i += 256) lh[i] = 0;
    __syncthreads();
    int stride = gridDim.x * 256;
    for (int i = blockIdx.x * 256 + threadIdx.x; i < M4; i += stride) {
        float4 v = base[i];
        atomicAdd(&lh[fkey(v.x) >> BIN_SHIFT], 1u);
        atomicAdd(&lh[fkey(v.y) >> BIN_SHIFT], 1u);
        atomicAdd(&lh[fkey(v.z) >> BIN_SHIFT], 1u);
        atomicAdd(&lh[fkey(v.w) >> BIN_SHIFT], 1u);
    }
    __syncthreads();
    for (int i = threadIdx.x; i < BINS; i += 256) {
        u32 c = lh[i];
        if (c) atomicAdd(&hist[p * BINS + i], c);
    }
}

// ---------------- resolve: threshold bin B, G = #(keys above B), KF = 1000 - G ----------------
__global__ __launch_bounds__(256) void k_resolve(const u32* __restrict__ hist,
                                                 int* __restrict__ binB, int* __restrict__ kneed,
                                                 int* __restrict__ g0) {
    int p = blockIdx.x, t = threadIdx.x;
    __shared__ u32 seg[256];
    __shared__ u32 tail[SEGW];
    __shared__ int sgS; __shared__ u32 GS;
    u32 s = 0;
    const u32* hb = hist + p * BINS;
    int base = t * SEGW;
    for (int q = 0; q < SEGW; ++q) s += hb[base + q];
    seg[t] = s;
    __syncthreads();
    if (t == 0) {
        u32 G = 0; int sg = 255;
        for (; sg > 0; --sg) {
            if (G + seg[sg] >= (u32)K_PER_LVL) break;
            G += seg[sg];
        }
        sgS = sg; GS = G;
    }
    __syncthreads();
    int sg = sgS;
    if (t < SEGW) tail[t] = hb[sg * SEGW + t];
    __syncthreads();
    if (t == 0) {
        u32 G = GS; int B = sg * SEGW;
        for (int b = SEGW - 1; b >= 0; --b) {
            u32 c = tail[b];
            if (G + c >= (u32)K_PER_LVL) { B = sg * SEGW + b; break; }
            G += c;
        }
        binB[p] = B;
        kneed[p] = K_PER_LVL - (int)G;   // KF taken from boundary bin
        g0[p] = (int)G;                  // count strictly above bin B
    }
}

// ---------------- compact: block-local LDS staging, ONE reservation atomic per block ----------------
__global__ __launch_bounds__(256) void k_compact(Ptrs P, const int* __restrict__ binB,
                                                 u32* gcnt, u32* ecnt,
                                                 int* __restrict__ sel, u64* __restrict__ eq) {
    int p = blockIdx.y; int l = p % 5; int n = p / 5;
    int M4 = c_LM[l] >> 2; int gg = c_LM[l] / 3;
    const float4* base = (const float4*)(P.o[l] + (size_t)n * c_LM[l]);
    int B = binB[p];
    __shared__ u32 lsel[CBUF];
    __shared__ u64 leq[CBUF];
    __shared__ u32 cSel, cEq, baseSel, baseEq;
    if (threadIdx.x == 0) { cSel = 0; cEq = 0; }
    __syncthreads();
    int stride = gridDim.x * 256;
    for (int i4 = blockIdx.x * 256 + threadIdx.x; i4 < M4; i4 += stride) {
        float4 v = base[i4];
        float vv[4] = {v.x, v.y, v.z, v.w};
        #pragma unroll
        for (int q = 0; q < 4; ++q) {
            u32 k = fkey(vv[q]);
            int bin = (int)(k >> BIN_SHIFT);
            if (bin < B) continue;
            int i = i4 * 4 + q;
            // input linear i = a*gg + pix ; flattened m = pix*3 + a  (h,w,a order)
            int a = i / gg; int pix = i - a * gg; int m = pix * 3 + a;
            if (bin > B) {
                u32 t = atomicAdd(&cSel, 1u);
                if (t < CBUF) lsel[t] = (u32)m;
                else { u32 pos = atomicAdd(&gcnt[p], 1u); sel[p * K_PER_LVL + pos] = m; }
            } else {
                u64 pk = ((u64)k << 20) | (u64)(0xFFFFFu ^ (u32)m);
                u32 t = atomicAdd(&cEq, 1u);
                if (t < CBUF) leq[t] = pk;
                else { u32 e = atomicAdd(&ecnt[p], 1u); if (e < EQ_CAP) eq[(size_t)p * EQ_CAP + e] = pk; }
            }
        }
    }
    __syncthreads();
    if (threadIdx.x == 0) {
        u32 ns = cSel < CBUF ? cSel : CBUF;
        u32 ne = cEq < CBUF ? cEq : CBUF;
        baseSel = ns ? atomicAdd(&gcnt[p], ns) : 0u;
        baseEq  = ne ? atomicAdd(&ecnt[p], ne) : 0u;
    }
    __syncthreads();
    u32 ns = cSel < CBUF ? cSel : CBUF;
    u32 ne = cEq < CBUF ? cEq : CBUF;
    for (u32 i = threadIdx.x; i < ns; i += 256) sel[p * K_PER_LVL + baseSel + i] = (int)lsel[i];
    for (u32 i = threadIdx.x; i < ne; i += 256) {
        u32 slot = baseEq + i;
        if (slot < EQ_CAP) eq[(size_t)p * EQ_CAP + slot] = leq[i];
    }
}

// ---------------- boundary bin: rank-by-count selection (keys unique), take KF lowest ranks ----------------
__global__ __launch_bounds__(256) void k_eqsel(const u32* __restrict__ ecnt, const int* __restrict__ kneed,
                                               const int* __restrict__ g0,
                                               const u64* __restrict__ eq, int* __restrict__ sel) {
    int p = blockIdx.x, t = threadIdx.x;
    int E = (int)ecnt[p]; if (E > EQ_CAP) E = EQ_CAP;
    int KF = kneed[p]; int G0 = g0[p];
    __shared__ u64 a[EQ_CAP];
    for (int i = t; i < E; i += 256) a[i] = eq[(size_t)p * EQ_CAP + i];
    __syncthreads();
    u64 mine[8]; int rk[8];
    #pragma unroll
    for (int q = 0; q < 8; ++q) {
        int i = t + q * 256;
        mine[q] = (i < E) ? a[i] : 0ULL;
        rk[q] = 0;
    }
    for (int j = 0; j < E; ++j) {
        u64 v = a[j];                            // uniform index -> LDS broadcast
        #pragma unroll
        for (int q = 0; q < 8; ++q) rk[q] += (v > mine[q]) ? 1 : 0;
    }
    #pragma unroll
    for (int q = 0; q < 8; ++q) {
        int i = t + q * 256;
        if (i < E && rk[q] < KF) {
            int m = (int)(0xFFFFFu ^ (u32)(mine[q] & 0xFFFFFu));
            sel[p * K_PER_LVL + G0 + rk[q]] = m;
        }
    }
}

// ---------------- featurize: anchors + decode + clip + score + 64b order key ----------------
__global__ void k_feat(Ptrs P, const int* __restrict__ sel, u64* __restrict__ key64,
                       float* __restrict__ csc, float* __restrict__ cbox, float* __restrict__ cobox) {
    int tid = blockIdx.x * 256 + threadIdx.x;
    if (tid >= NIMG * KTOT) return;
    int p = tid / K_PER_LVL, s = tid - p * K_PER_LVL;
    int n = p / 5, l = p % 5;
    int G = c_LG[l], S = c_LS[l], Z = c_LZ[l];
    int gg = G * G;
    int m = sel[p * K_PER_LVL + s];
    int a = m % 3; int pix = m / 3; int h = pix / G; int w = pix - h * G;

    // anchor base: hr=sqrt(ar), wr=1/hr, round-half-even (matches jnp f32)
    const float ars[3] = {0.5f, 1.0f, 2.0f};
    float ar = ars[a];
    float hr = sqrtf(ar), wr = 1.0f / hr;
    float wsz = wr * (float)Z, hsz = hr * (float)Z;
    float bx1 = rintf(-0.5f * wsz), by1 = rintf(-0.5f * hsz);
    float bx2 = rintf(0.5f * wsz),  by2 = rintf(0.5f * hsz);
    float sx = (float)(w * S), sy = (float)(h * S);
    float ax1 = sx + bx1, ay1 = sy + by1, ax2 = sx + bx2, ay2 = sy + by2;
    float wa = ax2 - ax1, ha = ay2 - ay1;
    float cxa = ax1 + 0.5f * wa, cya = ay1 + 0.5f * ha;

    const float* bb = P.b[l] + (size_t)n * 12 * gg;
    float dx = bb[(a * 4 + 0) * gg + pix];
    float dy = bb[(a * 4 + 1) * gg + pix];
    const float CLIPV = 4.135166556742356f;  // log(1000/16)
    float dw = fminf(bb[(a * 4 + 2) * gg + pix], CLIPV);
    float dh = fminf(bb[(a * 4 + 3) * gg + pix], CLIPV);
    float cx = dx * wa + cxa, cy = dy * ha + cya;
    float ww = expf(dw) * wa, hh = expf(dh) * ha;
    float x1 = cx - 0.5f * ww, y1 = cy - 0.5f * hh;
    float x2 = cx + 0.5f * ww, y2 = cy + 0.5f * hh;
    x1 = fminf(fmaxf(x1, 0.f), 2048.f);
    y1 = fminf(fmaxf(y1, 0.f), 2048.f);
    x2 = fminf(fmaxf(x2, 0.f), 2048.f);
    y2 = fminf(fmaxf(y2, 0.f), 2048.f);

    float raw = P.o[l][(size_t)n * 3 * gg + a * gg + pix];
    float sc = 1.0f / (1.0f + expf(-raw));
    bool keep = (x2 - x1 >= 1e-3f) && (y2 - y1 >= 1e-3f) && (sc > 0.0f);

    int slot = n * KTOT + l * K_PER_LVL + s;
    // total order key: raw desc, then (level asc, m asc) == reference concat-position order
    u32 tb = ((u32)l << 20) | (u32)m;          // m < 2^20, l < 8  -> 23 bits, unique
    u32 kk = keep ? fkey(raw) : 0u;            // invalid sinks below every valid (finite raw)
    key64[slot] = ((u64)kk << 23) | (u64)(tb ^ 0x7FFFFFu);

    csc[slot] = keep ? sc : -INFINITY;
    cbox[slot * 4 + 0] = x1; cbox[slot * 4 + 1] = y1;
    cbox[slot * 4 + 2] = x2; cbox[slot * 4 + 3] = y2;
    float off = 4097.0f * (float)l;            // lvl * (W+H+1), batched_nms offset
    cobox[slot * 4 + 0] = x1 + off; cobox[slot * 4 + 1] = y1 + off;
    cobox[slot * 4 + 2] = x2 + off; cobox[slot * 4 + 3] = y2 + off;
}

// ---------------- fused: rank partial counts + IoU edges on UNSORTED boxes ----------------
// Edge pairs are rank-independent (IoU symmetric, same box values); computing them
// on cobox lets rankp+edge share one dispatch. Edge tiles: i-tile 256 x j-tile 64,
// coarse triangle skip (bj >= 4*bi). k_nms remaps pairs via rank[].
__global__ __launch_bounds__(256) void k_redge(const u64* __restrict__ key64, u32* __restrict__ rpart,
                                               const float* __restrict__ cobox,
                                               u32* __restrict__ gE, u32* __restrict__ gPairs) {
    int n = blockIdx.y;
    int x = blockIdx.x;
    __shared__ u64 kj[RNK_JB];
    __shared__ float cb[64][4];
    if (x < RNK_TILES) {
        // ---- rank partials ----
        int i0 = (x / 20) * RNK_IB;
        int j0 = (x % 20) * RNK_JB;
        const u64* kb = key64 + (size_t)n * KTOT;
        for (int t = threadIdx.x; t < RNK_JB; t += 256) kj[t] = kb[j0 + t];
        __syncthreads();
        int i1 = i0 + threadIdx.x, i2 = i1 + 256;
        u64 k1 = (i1 < KTOT) ? kb[i1] : ~0ULL;
        u64 k2 = (i2 < KTOT) ? kb[i2] : ~0ULL;
        u32 r1 = 0, r2 = 0;
        #pragma unroll 10
        for (int j = 0; j < RNK_JB; ++j) {
            u64 v = kj[j];
            r1 += (v > k1) ? 1u : 0u;
            r2 += (v > k2) ? 1u : 0u;
        }
        u32* rp = rpart + (size_t)(x % 20) * (NIMG * KTOT) + n * KTOT;
        if (i1 < KTOT) rp[i1] = r1;
        if (i2 < KTOT) rp[i2] = r2;
        return;
    }
    // ---- edge tile: decode e -> (bi, bj) with bj in [4*bi, 78] ----
    int e = x - RNK_TILES, bi = 0;
    while (true) { int c = 79 - 4 * bi; if (e < c) break; e -= c; ++bi; }
    int bj = 4 * bi + e;
    int i = bi * 256 + threadIdx.x;
    int j0 = bj * 64;
    if (threadIdx.x < 64) {
        int jl = j0 + threadIdx.x;
        if (jl < KTOT) {
            cb[threadIdx.x][0] = cobox[(size_t)(n * KTOT + jl) * 4 + 0];
            cb[threadIdx.x][1] = cobox[(size_t)(n * KTOT + jl) * 4 + 1];
            cb[threadIdx.x][2] = cobox[(size_t)(n * KTOT + jl) * 4 + 2];
            cb[threadIdx.x][3] = cobox[(size_t)(n * KTOT + jl) * 4 + 3];
        } else {
            cb[threadIdx.x][0] = 0.f; cb[threadIdx.x][1] = 0.f;
            cb[threadIdx.x][2] = 0.f; cb[threadIdx.x][3] = 0.f;
        }
    }
    __syncthreads();
    if (i >= KTOT) return;
    float x1 = cobox[(size_t)(n * KTOT + i) * 4 + 0];
    float y1 = cobox[(size_t)(n * KTOT + i) * 4 + 1];
    float x2 = cobox[(size_t)(n * KTOT + i) * 4 + 2];
    float y2 = cobox[(size_t)(n * KTOT + i) * 4 + 3];
    float areai = fmaxf(x2 - x1, 0.f) * fmaxf(y2 - y1, 0.f);
    int lim = KTOT - j0; if (lim > 64) lim = 64;
    for (int jj = 0; jj < lim; ++jj) {
        int j = j0 + jj;
        if (j <= i) continue;
        float bx1 = cb[jj][0], by1 = cb[jj][1], bx2 = cb[jj][2], by2 = cb[jj][3];
        float areaj = fmaxf(bx2 - bx1, 0.f) * fmaxf(by2 - by1, 0.f);
        float ltx = fmaxf(x1, bx1), lty = fmaxf(y1, by1);
        float rbx = fminf(x2, bx2), rby = fminf(y2, by2);
        float iw = fmaxf(rbx - ltx, 0.f), ih = fmaxf(rby - lty, 0.f);
        float inter = iw * ih;
        float iou = inter / (areai + areaj - inter + 1e-9f);
        if (iou > 0.7f) {
            u32 pos = atomicAdd(&gE[n], 1u);
            if (pos < ECAP) gPairs[(size_t)n * ECAP + pos] = ((u32)i << 13) | (u32)j;  // original indices
        }
    }
}

// ---------------- rank part 2: sum partials, scatter payload + rank[] ----------------
__global__ __launch_bounds__(256) void k_scat(const u32* __restrict__ rpart, const float* __restrict__ csc,
                       const float* __restrict__ cbox,
                       float* __restrict__ ssc, float* __restrict__ sbox, u32* __restrict__ rankArr) {
    int n = blockIdx.y;
    int i = blockIdx.x * 256 + threadIdx.x;
    if (i >= KTOT) return;
    int idx = n * KTOT + i;
    u32 rank = 0;
    #pragma unroll
    for (int jb = 0; jb < RNK_NJ; ++jb) rank += rpart[(size_t)jb * (NIMG * KTOT) + idx];
    rankArr[idx] = rank;
    int src = idx, dst = n * KTOT + (int)rank;
    ssc[dst] = csc[src];
    sbox[dst * 4 + 0] = cbox[src * 4 + 0]; sbox[dst * 4 + 1] = cbox[src * 4 + 1];
    sbox[dst * 4 + 2] = cbox[src * 4 + 2]; sbox[dst * 4 + 3] = cbox[src * 4 + 3];
}

// ---------------- greedy NMS sweep over sparse CSR (pairs remapped via rank[]) ----------------
__global__ __launch_bounds__(256, 1) void k_nms(const float* __restrict__ ssc,
                      const float* __restrict__ sbox, const u32* __restrict__ rankArr,
                      const u32* __restrict__ gE, const u32* __restrict__ gPairs,
                      u16* __restrict__ gEdges, float* __restrict__ out) {
    int n = blockIdx.x, tid = threadIdx.x;
    int lane = tid & 63, wv = tid >> 6;          // 4 waves
    __shared__ u32 cnt[KTOT];                    // 20 KB (count, then fill cursor)
    __shared__ u32 offs[KTOT + 1];               // 20 KB
    __shared__ u16 edges[LECAP];                 // 48 KB
    __shared__ u32 rem32[160];                   // dead bitmap (2 u32 per 64-word)
    __shared__ u32 colLo[64], colHi[64];
    __shared__ u32 scanb[256];
    __shared__ int picksS;

    for (int i = tid; i < KTOT; i += 256) cnt[i] = 0;
    if (tid < 160) rem32[tid] = 0xFFFFFFFFu;
    __syncthreads();
    for (int w = wv; w < 79; w += 4) {
        int i = w * 64 + lane;
        bool dead = (i >= KTOT) || !(ssc[n * KTOT + i] > -INFINITY);
        u64 db = __ballot(dead);
        if (lane == 0) { rem32[2 * w] = (u32)db; rem32[2 * w + 1] = (u32)(db >> 32); }
    }
    __syncthreads();

    // ---- CSR build: pairs are (a,b) original indices; direct by rank ----
    int E = (int)gE[n]; if (E > ECAP) E = ECAP;
    for (int k = tid; k < E; k += 256) {
        u32 p = gPairs[(size_t)n * ECAP + k];
        u32 ra = rankArr[n * KTOT + (p >> 13)], rb = rankArr[n * KTOT + (p & 0x1FFFu)];
        u32 src = ra < rb ? ra : rb;
        atomicAdd(&cnt[src], 1u);
    }
    __syncthreads();
    u32 s = 0; int base = tid * 20;
    if (tid < 250) for (int q = 0; q < 20; ++q) s += cnt[base + q];
    scanb[tid] = s;
    __syncthreads();
    for (int off = 1; off < 256; off <<= 1) {
        u32 v = (tid >= off) ? scanb[tid - off] : 0;
        __syncthreads();
        scanb[tid] += v;
        __syncthreads();
    }
    u32 tbase = (tid == 0) ? 0u : scanb[tid - 1];
    if (tid < 250) {
        u32 run = tbase;
        for (int q = 0; q < 20; ++q) { offs[base + q] = run; run += cnt[base + q]; }
    }
    if (tid == 0) offs[KTOT] = scanb[255];
    __syncthreads();
    for (int i = tid; i < KTOT; i += 256) cnt[i] = 0;
    __syncthreads();
    for (int k = tid; k < E; k += 256) {
        u32 p = gPairs[(size_t)n * ECAP + k];
        u32 ra = rankArr[n * KTOT + (p >> 13)], rb = rankArr[n * KTOT + (p & 0x1FFFu)];
        u32 src = ra < rb ? ra : rb, dst = ra < rb ? rb : ra;
        u32 slot = offs[src] + atomicAdd(&cnt[src], 1u);
        if (slot < LECAP) edges[slot] = (u16)dst;
        else gEdges[(size_t)n * ECAP + slot] = (u16)dst;
    }
    __syncthreads();

    // ---- wave-0 sweep: rank order, no global memory on the critical path ----
    if (wv == 0) {
        int picks = 0;
        for (int w = 0; w < 79 && picks < 1000; ++w) {
            u64 rw = ((u64)rem32[2 * w + 1] << 32) | rem32[2 * w];
            u64 alive = ~rw;
            if (alive == 0ULL) continue;
            int c = w * 64 + lane;
            bool amAlive = ((alive >> lane) & 1ULL) != 0ULL;
            int e0 = 0, e1 = 0;
            if (amAlive) { e0 = (int)offs[c]; e1 = (int)offs[c + 1]; }
            colLo[lane] = 0; colHi[lane] = 0;
            bool anyIntra = false;
            for (int k = e0; k < e1; ++k) {
                int dst = (k < LECAP) ? (int)edges[k] : (int)gEdges[(size_t)n * ECAP + k];
                if ((dst >> 6) == w) {
                    if (lane < 32) atomicOr(&colLo[dst & 63], 1u << lane);
                    else           atomicOr(&colHi[dst & 63], 1u << (lane - 32));
                    anyIntra = true;
                }
            }
            u64 cm;
            if (__ballot(anyIntra) == 0ULL) {
                cm = alive;
            } else {
                u64 col = ((u64)colHi[lane] << 32) | colLo[lane];
                cm = 0ULL;
                for (int e = 0; e < 64; ++e) {
                    if (!((alive >> e) & 1ULL)) continue;
                    u64 ce = __shfl(col, e);
                    if ((cm & ce) == 0ULL) cm |= (1ULL << e);
                }
            }
            int allowed = 1000 - picks;
            int ncom = __popcll(cm);
            while (ncom > allowed) { cm &= ~(1ULL << (63 - __clzll(cm))); --ncom; }
            if ((cm >> lane) & 1ULL) {
                int pos = picks + (int)__popcll(cm & ((1ULL << lane) - 1ULL));
                const float* bp = &sbox[(size_t)(n * KTOT + c) * 4];
                float* op = &out[(n * 1000 + pos) * 5];
                op[0] = bp[0]; op[1] = bp[1]; op[2] = bp[2]; op[3] = bp[3];
                op[4] = ssc[n * KTOT + c];
                for (int k = e0; k < e1; ++k) {
                    int dst = (k < LECAP) ? (int)edges[k] : (int)gEdges[(size_t)n * ECAP + k];
                    atomicOr(&rem32[dst >> 5], 1u << (dst & 31));
                }
            }
            picks += ncom;
        }
        if (lane == 0) picksS = picks;
    }
    __syncthreads();
    int picksF = picksS;
    int basec = (n * 1000 + picksF) * 5, cntz = (1000 - picksF) * 5;
    for (int t = tid; t < cntz; t += 256) out[basec + t] = 0.f;
}

// ---------------- workspace layout ----------------
constexpr size_t OFF_HIST   = 0;                                       // zeroed region start
constexpr size_t OFF_GCNT   = OFF_HIST + 10 * BINS * 4;
constexpr size_t OFF_ECNT   = OFF_GCNT + 64;
constexpr size_t OFF_GEC    = OFF_ECNT + 64;                           // edge counters (2 u32)
constexpr size_t ZERO_WORDS = (10 * BINS * 4 + 192) / 4;               // hist + gcnt + ecnt + gec
constexpr size_t OFF_BINB   = OFF_GEC + 64;
constexpr size_t OFF_KNEED  = OFF_BINB + 64;
constexpr size_t OFF_G0     = OFF_KNEED + 64;
constexpr size_t OFF_SEL    = OFF_G0 + 64;
constexpr size_t OFF_EQ     = OFF_SEL + 10 * K_PER_LVL * 4;            // 8-aligned
constexpr size_t OFF_KEY64  = OFF_EQ + (size_t)10 * EQ_CAP * 8;
constexpr size_t OFF_CSC    = OFF_KEY64 + (size_t)NIMG * KTOT * 8;
constexpr size_t OFF_CBOX   = OFF_CSC + (size_t)NIMG * KTOT * 4;
constexpr size_t OFF_COBOX  = OFF_CBOX + (size_t)NIMG * KTOT * 16;
constexpr size_t OFF_SSC    = OFF_COBOX + (size_t)NIMG * KTOT * 16;
constexpr size_t OFF_SBOX   = OFF_SSC + (size_t)NIMG * KTOT * 4;
constexpr size_t OFF_RANK   = OFF_SBOX + (size_t)NIMG * KTOT * 16;     // u32[NIMG*KTOT]
constexpr size_t OFF_PAIRS  = OFF_RANK + (size_t)NIMG * KTOT * 4;      // u32[NIMG*ECAP]
constexpr size_t OFF_ESPILL = OFF_PAIRS + (size_t)NIMG * ECAP * 4;     // u16[NIMG*ECAP]
constexpr size_t OFF_RPART  = OFF_ESPILL + (size_t)NIMG * ECAP * 2;    // u32[RNK_NJ][NIMG*KTOT]
constexpr size_t WS_NEEDED  = OFF_RPART + (size_t)RNK_NJ * NIMG * KTOT * 4;

extern "C" void kernel_launch(void* const* d_in, const int* in_sizes, int n_in,
                              void* d_out, int out_size, void* d_ws, size_t ws_size,
                              hipStream_t stream) {
    if (ws_size < WS_NEEDED) return;

    // Detect input ordering from sizes: dict order interleaves (obj0,box0,...)
    bool dictOrder = (in_sizes[1] > in_sizes[0]);
    Ptrs P;
    for (int l = 0; l < 5; ++l) {
        P.o[l] = (const float*)d_in[dictOrder ? (2 * l)     : l];
        P.b[l] = (const float*)d_in[dictOrder ? (2 * l + 1) : (5 + l)];
    }
    char* ws = (char*)d_ws;
    u32*   hist   = (u32*)(ws + OFF_HIST);
    u32*   gcnt   = (u32*)(ws + OFF_GCNT);
    u32*   ecnt   = (u32*)(ws + OFF_ECNT);
    u32*   gec    = (u32*)(ws + OFF_GEC);
    int*   binB   = (int*)(ws + OFF_BINB);
    int*   kneed  = (int*)(ws + OFF_KNEED);
    int*   g0     = (int*)(ws + OFF_G0);
    int*   sel    = (int*)(ws + OFF_SEL);
    u64*   eq     = (u64*)(ws + OFF_EQ);
    u64*   key64  = (u64*)(ws + OFF_KEY64);
    float* csc    = (float*)(ws + OFF_CSC);
    float* cbox   = (float*)(ws + OFF_CBOX);
    float* cobox  = (float*)(ws + OFF_COBOX);
    float* ssc    = (float*)(ws + OFF_SSC);
    float* sbox   = (float*)(ws + OFF_SBOX);
    u32*   rankA  = (u32*)(ws + OFF_RANK);
    u32*   pairs  = (u32*)(ws + OFF_PAIRS);
    u16*   espill = (u16*)(ws + OFF_ESPILL);
    u32*   rpart  = (u32*)(ws + OFF_RPART);
    float* out    = (float*)d_out;

    k_zero<<<dim3(64), 256, 0, stream>>>(hist, (int)ZERO_WORDS);
    k_hist<<<dim3(32, 10), 256, 0, stream>>>(P, hist);
    k_resolve<<<10, 256, 0, stream>>>(hist, binB, kneed, g0);
    k_compact<<<dim3(64, 10), 256, 0, stream>>>(P, binB, gcnt, ecnt, sel, eq);
    k_eqsel<<<10, 256, 0, stream>>>(ecnt, kneed, g0, eq, sel);
    k_feat<<<dim3((NIMG * KTOT + 255) / 256), 256, 0, stream>>>(P, sel, key64, csc, cbox, cobox);
    k_redge<<<dim3(RNK_TILES + EDGE_TILES, NIMG), 256, 0, stream>>>(key64, rpart, cobox, gec, pairs);
    k_scat<<<dim3((KTOT + 255) / 256, NIMG), 256, 0, stream>>>(rpart, csc, cbox, ssc, sbox, rankA);
    k_nms<<<NIMG, 256, 0, stream>>>(ssc, sbox, rankA, gec, pairs, espill, out);
}